// Round 1
// baseline (1608.155 us; speedup 1.0000x reference)
//
#include <hip/hip_runtime.h>
#include <cstdint>
#include <cstddef>

#define DEVINL __device__ __forceinline__

typedef __bf16 bf16x8 __attribute__((ext_vector_type(8)));
typedef float f32x4 __attribute__((ext_vector_type(4)));

static constexpr int NN = 10000;     // nodes
static constexpr int NE = 80000;     // edges
static constexpr int IN_DIM = 1024;
static constexpr int HID = 4096;
static constexpr int OUTD = 256;
static constexpr int M_PAD = 10112;  // 79*128 (also 158*64)

// fp32 -> bf16 round-nearest-even
DEVINL unsigned short f2bf(float f) {
  unsigned int u = __builtin_bit_cast(unsigned int, f);
  u += 0x7fffu + ((u >> 16) & 1u);
  return (unsigned short)(u >> 16);
}

// async global->LDS, 16B per lane; LDS dest is wave-uniform base + lane*16
DEVINL void ld_lds16(const void* g, void* l) {
  __builtin_amdgcn_global_load_lds(
      (const __attribute__((address_space(1))) unsigned int*)g,
      (__attribute__((address_space(3))) unsigned int*)l, 16, 0, 0);
}

// ---------------- degree count ----------------
__global__ void deg_kernel(const int* __restrict__ dst, float* __restrict__ cnt) {
  int e = blockIdx.x * 256 + threadIdx.x;
  if (e < NE) atomicAdd(&cnt[dst[e]], 1.0f);
}

// ---------------- layer-1 scatter: agg1[dst] += x[src], 1024-wide ----------------
__global__ void scatter1_kernel(const float* __restrict__ x, const int* __restrict__ src,
                                const int* __restrict__ dst, float* __restrict__ agg1) {
  int e = blockIdx.x;
  int t = threadIdx.x;  // 0..255, 4 floats each
  int s = src[e], d = dst[e];
  float4 v = ((const float4*)(x + (size_t)s * IN_DIM))[t];
  float* a = agg1 + (size_t)d * IN_DIM + t * 4;
  atomicAdd(a + 0, v.x);
  atomicAdd(a + 1, v.y);
  atomicAdd(a + 2, v.z);
  atomicAdd(a + 3, v.w);
}

// ---------------- build A1 = [mean1 | x] in bf16, rows 0..9999 ----------------
__global__ void build_a1_kernel(const float* __restrict__ agg1, const float* __restrict__ cnt,
                                const float* __restrict__ x, unsigned short* __restrict__ A1) {
  int i = blockIdx.x;
  int t = threadIdx.x;  // 256 threads x float4
  float inv = 1.0f / fmaxf(cnt[i], 1.0f);
  float4 a = ((const float4*)(agg1 + (size_t)i * IN_DIM))[t];
  float4 b = ((const float4*)(x + (size_t)i * IN_DIM))[t];
  ushort4 pa, pb;
  pa.x = f2bf(a.x * inv); pa.y = f2bf(a.y * inv); pa.z = f2bf(a.z * inv); pa.w = f2bf(a.w * inv);
  pb.x = f2bf(b.x); pb.y = f2bf(b.y); pb.z = f2bf(b.z); pb.w = f2bf(b.w);
  unsigned short* row = A1 + (size_t)i * 2048;
  ((ushort4*)row)[t] = pa;             // cols 0..1023 = mean
  ((ushort4*)(row + 1024))[t] = pb;    // cols 1024..2047 = x
}

// ---------------- weight converts (fp32 -> bf16, concatenated layouts) ----------------
// w1cat [4096][2048]: row n = [W1_l row n | W1_r row n]
__global__ void conv_w1_kernel(const float* __restrict__ Wl, const float* __restrict__ Wr,
                               unsigned short* __restrict__ w1cat) {
  int g = blockIdx.x * 256 + threadIdx.x;  // float4 groups: 4096*512
  int n = g >> 9;
  int kg = g & 511;
  const float* s = (kg < 256) ? (Wl + (size_t)n * 1024 + kg * 4)
                              : (Wr + (size_t)n * 1024 + (kg - 256) * 4);
  float4 v = *(const float4*)s;
  ushort4 p = {f2bf(v.x), f2bf(v.y), f2bf(v.z), f2bf(v.w)};
  ((ushort4*)w1cat)[g] = p;
}

// w2cat [512][4096]: rows 0..255 = W2_l, rows 256..511 = W2_r
__global__ void conv_w2_kernel(const float* __restrict__ Wl, const float* __restrict__ Wr,
                               unsigned short* __restrict__ w2cat) {
  int g = blockIdx.x * 256 + threadIdx.x;  // float4 groups: 512*1024
  int n = g >> 10;
  int kg = g & 1023;
  const float* s = (n < 256) ? (Wl + (size_t)n * 4096 + kg * 4)
                             : (Wr + (size_t)(n - 256) * 4096 + kg * 4);
  float4 v = *(const float4*)s;
  ushort4 p = {f2bf(v.x), f2bf(v.y), f2bf(v.z), f2bf(v.w)};
  ((ushort4*)w2cat)[g] = p;
}

// ---------------- bf16 MFMA GEMM: C[M_PAD,N] = A[M_PAD,K] * Bt[N,K]^T ----------------
// BN = 128 fixed; BM in {64,128}; 4 waves in 2x2 arrangement.
// LDS tiles row-major [rows][32] bf16 with XOR slot swizzle: slot(q,r) = q ^ ((r>>1)&3)
// so ds_read_b128 lands at <=2-way bank aliasing (free) while global_load_lds keeps its
// mandatory contiguous lane order (source chunk is swizzled instead).
template <int BM, int K, int N, bool EPI_RELU_BF16>
__global__ __launch_bounds__(256) void gemm_kernel(const unsigned short* __restrict__ A,
                                                   const unsigned short* __restrict__ Bt,
                                                   const float* __restrict__ bias,
                                                   void* __restrict__ Cout) {
  constexpr int BN = 128;
  constexpr int MI = BM / 32;  // 16-row tiles per wave (m)
  constexpr int NI = 4;        // 16-col tiles per wave (n)
  constexpr int SA = BM / 64;  // A staging segments per wave (1024B each)
  constexpr int SB = BN / 64;
  __shared__ unsigned short Asm[BM * 32];
  __shared__ unsigned short Bsm[BN * 32];

  const int tid = threadIdx.x;
  const int lane = tid & 63;
  const int wave = tid >> 6;
  const int quad = lane >> 4;
  const int l16 = lane & 15;
  const int wm = (wave & 1) * (BM / 2);
  const int wn = (wave >> 1) * 64;
  const long tm0 = (long)blockIdx.x * BM;
  const long tn0 = (long)blockIdx.y * BN;

  f32x4 acc[MI][NI];
#pragma unroll
  for (int i = 0; i < MI; ++i)
#pragma unroll
    for (int j = 0; j < NI; ++j) acc[i][j] = (f32x4){0.f, 0.f, 0.f, 0.f};

  // staging descriptors: chunk c -> row r = c>>2, slot = c&3, source chunk g = slot^((r>>1)&3)
  const unsigned short* aSrc[SA];
  unsigned short* aDst[SA];
  const unsigned short* bSrc[SB];
  unsigned short* bDst[SB];
#pragma unroll
  for (int s = 0; s < SA; ++s) {
    int c = s * 256 + wave * 64 + lane;
    int r = c >> 2;
    int g = (c & 3) ^ ((r >> 1) & 3);
    aSrc[s] = A + (size_t)(tm0 + r) * K + g * 8;
    aDst[s] = Asm + s * 2048 + wave * 512;  // wave-uniform base
  }
#pragma unroll
  for (int s = 0; s < SB; ++s) {
    int c = s * 256 + wave * 64 + lane;
    int r = c >> 2;
    int g = (c & 3) ^ ((r >> 1) & 3);
    bSrc[s] = Bt + (size_t)(tn0 + r) * K + g * 8;
    bDst[s] = Bsm + s * 2048 + wave * 512;
  }

  const int srd = quad ^ ((l16 >> 1) & 3);  // read-slot swizzle (row bits 1..2 == l16 bits 1..2)

  for (int k0 = 0; k0 < K; k0 += 32) {
#pragma unroll
    for (int s = 0; s < SA; ++s) ld_lds16(aSrc[s] + k0, aDst[s]);
#pragma unroll
    for (int s = 0; s < SB; ++s) ld_lds16(bSrc[s] + k0, bDst[s]);
    __syncthreads();  // drains vmcnt -> LDS tiles complete

    bf16x8 af[MI], bv[NI];
#pragma unroll
    for (int i = 0; i < MI; ++i) {
      int ra = wm + i * 16 + l16;
      af[i] = *(const bf16x8*)(Asm + ra * 32 + srd * 8);
    }
#pragma unroll
    for (int j = 0; j < NI; ++j) {
      int rb = wn + j * 16 + l16;
      bv[j] = *(const bf16x8*)(Bsm + rb * 32 + srd * 8);
    }
#pragma unroll
    for (int i = 0; i < MI; ++i)
#pragma unroll
      for (int j = 0; j < NI; ++j)
        acc[i][j] = __builtin_amdgcn_mfma_f32_16x16x32_bf16(af[i], bv[j], acc[i][j], 0, 0, 0);
    __syncthreads();  // LDS reads done before next stage overwrites
  }

  // epilogue: C/D layout col = lane&15, row = quad*4 + reg
  if (EPI_RELU_BF16) {
    unsigned short* C = (unsigned short*)Cout;
#pragma unroll
    for (int i = 0; i < MI; ++i) {
      long m0 = tm0 + wm + i * 16 + quad * 4;
#pragma unroll
      for (int j = 0; j < NI; ++j) {
        int n = (int)tn0 + wn + j * 16 + l16;
        float bvs = bias[n];
#pragma unroll
        for (int r = 0; r < 4; ++r) {
          float v = acc[i][j][r] + bvs;
          v = fmaxf(v, 0.0f);
          C[(size_t)(m0 + r) * N + n] = f2bf(v);
        }
      }
    }
  } else {
    float* C = (float*)Cout;
#pragma unroll
    for (int i = 0; i < MI; ++i) {
      long m0 = tm0 + wm + i * 16 + quad * 4;
#pragma unroll
      for (int j = 0; j < NI; ++j) {
        int n = (int)tn0 + wn + j * 16 + l16;
#pragma unroll
        for (int r = 0; r < 4; ++r) C[(size_t)(m0 + r) * N + n] = acc[i][j][r];
      }
    }
  }
}

// ---------------- layer-2 scatter: agg2[dst] += p_l[src] (256-wide) ----------------
__global__ void scatter2_kernel(const float* __restrict__ C2, const int* __restrict__ src,
                                const int* __restrict__ dst, float* __restrict__ agg2) {
  int e = blockIdx.x;
  int t = threadIdx.x;  // 0..255
  int s = src[e], d = dst[e];
  float v = C2[(size_t)s * 512 + t];
  atomicAdd(agg2 + (size_t)d * OUTD + t, v);
}

// ---------------- final: mean + bias + p_r, log_softmax over 256 ----------------
__global__ void final_kernel(const float* __restrict__ agg2, const float* __restrict__ cnt,
                             const float* __restrict__ b2, const float* __restrict__ C2,
                             float* __restrict__ out) {
  int i = blockIdx.x;
  int t = threadIdx.x;  // 0..255
  float inv = 1.0f / fmaxf(cnt[i], 1.0f);
  float v = agg2[(size_t)i * OUTD + t] * inv + b2[t] + C2[(size_t)i * 512 + 256 + t];

  __shared__ float sm[4], ss[4];
  int w = t >> 6;
  float m = v;
#pragma unroll
  for (int o = 32; o > 0; o >>= 1) m = fmaxf(m, __shfl_xor(m, o, 64));
  if ((t & 63) == 0) sm[w] = m;
  __syncthreads();
  m = fmaxf(fmaxf(sm[0], sm[1]), fmaxf(sm[2], sm[3]));

  float e = __expf(v - m);
  float s = e;
#pragma unroll
  for (int o = 32; o > 0; o >>= 1) s += __shfl_xor(s, o, 64);
  if ((t & 63) == 0) ss[w] = s;
  __syncthreads();
  s = ss[0] + ss[1] + ss[2] + ss[3];

  out[(size_t)i * OUTD + t] = v - m - logf(s);
}

// ---------------- workspace layout (bytes) ----------------
// A1    [10112][2048] bf16 = 41,418,752   (later reused as C2 [10112][512] f32 = 20,709,376)
// w1cat [4096][2048] bf16  = 16,777,216
// h_b   [10112][4096] bf16 = 82,837,504   (first 40,960,000 B alias agg1 [10000][1024] f32)
// w2cat [512][4096] bf16   =  4,194,304
// agg2  [10000][256] f32   = 10,240,000
// cnt   [10000] f32        =      40,000
static constexpr size_t OFF_A1 = 0;
static constexpr size_t OFF_W1 = OFF_A1 + (size_t)M_PAD * 2048 * 2;
static constexpr size_t OFF_HB = OFF_W1 + (size_t)HID * 2048 * 2;
static constexpr size_t OFF_W2 = OFF_HB + (size_t)M_PAD * HID * 2;
static constexpr size_t OFF_AGG2 = OFF_W2 + (size_t)512 * HID * 2;
static constexpr size_t OFF_CNT = OFF_AGG2 + (size_t)NN * OUTD * 4;

extern "C" void kernel_launch(void* const* d_in, const int* in_sizes, int n_in,
                              void* d_out, int out_size, void* d_ws, size_t ws_size,
                              hipStream_t stream) {
  const float* x = (const float*)d_in[0];
  const int* ei = (const int*)d_in[1];
  const int* src = ei;
  const int* dst = ei + NE;
  const float* W1_l = (const float*)d_in[2];
  const float* b1_l = (const float*)d_in[3];
  const float* W1_r = (const float*)d_in[4];
  const float* W2_l = (const float*)d_in[5];
  const float* b2_l = (const float*)d_in[6];
  const float* W2_r = (const float*)d_in[7];
  float* out = (float*)d_out;

  char* ws = (char*)d_ws;
  unsigned short* A1 = (unsigned short*)(ws + OFF_A1);
  unsigned short* w1cat = (unsigned short*)(ws + OFF_W1);
  unsigned short* h_b = (unsigned short*)(ws + OFF_HB);
  float* agg1 = (float*)(ws + OFF_HB);  // alias: dead before h_b is written
  unsigned short* w2cat = (unsigned short*)(ws + OFF_W2);
  float* agg2 = (float*)(ws + OFF_AGG2);
  float* cnt = (float*)(ws + OFF_CNT);
  float* C2 = (float*)(ws + OFF_A1);  // alias: A1 dead after gemm1

  // zero accumulators + A1 pad rows (ws is poisoned 0xAA before every call)
  hipMemsetAsync(agg1, 0, (size_t)NN * IN_DIM * 4, stream);
  hipMemsetAsync(agg2, 0, (size_t)NN * OUTD * 4, stream);
  hipMemsetAsync(cnt, 0, (size_t)NN * 4, stream);
  hipMemsetAsync(A1 + (size_t)NN * 2048, 0, (size_t)(M_PAD - NN) * 2048 * 2, stream);

  deg_kernel<<<(NE + 255) / 256, 256, 0, stream>>>(dst, cnt);
  scatter1_kernel<<<NE, 256, 0, stream>>>(x, src, dst, agg1);
  conv_w1_kernel<<<(HID * 512) / 256, 256, 0, stream>>>(W1_l, W1_r, w1cat);
  conv_w2_kernel<<<(512 * 1024) / 256, 256, 0, stream>>>(W2_l, W2_r, w2cat);
  build_a1_kernel<<<NN, 256, 0, stream>>>(agg1, cnt, x, A1);

  // h = relu(A1 @ w1cat^T + b1)  -> bf16 [10112][4096]
  gemm_kernel<128, 2048, 4096, true>
      <<<dim3(M_PAD / 128, HID / 128), 256, 0, stream>>>(A1, w1cat, b1_l, h_b);
  // C2 = h @ w2cat^T -> f32 [10112][512]  (cols 0..255 = p_l, 256..511 = p_r)
  gemm_kernel<64, 4096, 512, false>
      <<<dim3(M_PAD / 64, 512 / 128), 256, 0, stream>>>(h_b, w2cat, nullptr, C2);

  scatter2_kernel<<<NE, 256, 0, stream>>>(C2, src, dst, agg2);
  final_kernel<<<NN, 256, 0, stream>>>(agg2, cnt, b2_l, C2, out);
}

// Round 2
// 556.826 us; speedup vs baseline: 2.8881x; 2.8881x over previous
//
#include <hip/hip_runtime.h>
#include <cstdint>
#include <cstddef>

#define DEVINL __device__ __forceinline__

typedef __bf16 bf16x8 __attribute__((ext_vector_type(8)));
typedef float f32x4 __attribute__((ext_vector_type(4)));

static constexpr int NN = 10000;     // nodes
static constexpr int NE = 80000;     // edges
static constexpr int IN_DIM = 1024;
static constexpr int HID = 4096;
static constexpr int OUTD = 256;
static constexpr int M_PAD = 10112;  // 79*128 (also 158*64)

// fp32 -> bf16 round-nearest-even
DEVINL unsigned short f2bf(float f) {
  unsigned int u = __builtin_bit_cast(unsigned int, f);
  u += 0x7fffu + ((u >> 16) & 1u);
  return (unsigned short)(u >> 16);
}

// async global->LDS, 16B per lane; LDS dest is wave-uniform base + lane*16
DEVINL void ld_lds16(const void* g, void* l) {
  __builtin_amdgcn_global_load_lds(
      (const __attribute__((address_space(1))) unsigned int*)g,
      (__attribute__((address_space(3))) unsigned int*)l, 16, 0, 0);
}

// ---------------- CSR build: degree count ----------------
__global__ void deg_kernel(const int* __restrict__ dst, int* __restrict__ deg) {
  int e = blockIdx.x * 256 + threadIdx.x;
  if (e < NE) atomicAdd(&deg[dst[e]], 1);
}

// one-block exclusive scan over NN degrees -> offs[0..NN]
__global__ __launch_bounds__(256) void scan_kernel(const int* __restrict__ deg,
                                                   int* __restrict__ offs) {
  __shared__ int part[256];
  constexpr int NPT = 40;  // 256*40 = 10240 >= NN
  int t = threadIdx.x;
  int base = t * NPT;
  int s = 0;
  for (int j = 0; j < NPT; ++j) {
    int n = base + j;
    s += (n < NN) ? deg[n] : 0;
  }
  part[t] = s;
  __syncthreads();
  for (int o = 1; o < 256; o <<= 1) {  // Hillis-Steele inclusive scan
    int v = (t >= o) ? part[t - o] : 0;
    __syncthreads();
    part[t] += v;
    __syncthreads();
  }
  int pre = (t > 0) ? part[t - 1] : 0;
  for (int j = 0; j < NPT; ++j) {
    int n = base + j;
    if (n < NN) {
      offs[n] = pre;
      pre += deg[n];
    }
  }
  if (t == 255) offs[NN] = part[255];  // == NE
}

// bin edges: csr_src[offs[dst] + fill[dst]++] = src
__global__ void bin_kernel(const int* __restrict__ src, const int* __restrict__ dst,
                           const int* __restrict__ offs, int* __restrict__ fill,
                           int* __restrict__ csr) {
  int e = blockIdx.x * 256 + threadIdx.x;
  if (e < NE) {
    int d = dst[e];
    int p = atomicAdd(&fill[d], 1);
    csr[offs[d] + p] = src[e];
  }
}

// ---------------- layer-1 gather: A1 = [mean_agg(x) | x] in bf16 ----------------
__global__ __launch_bounds__(256) void gather1_kernel(const float* __restrict__ x,
                                                      const int* __restrict__ offs,
                                                      const int* __restrict__ csr,
                                                      unsigned short* __restrict__ A1) {
  int i = blockIdx.x;
  int t = threadIdx.x;  // 256 threads x float4 = 1024 floats
  int beg = offs[i], end = offs[i + 1];
  float4 acc = {0.f, 0.f, 0.f, 0.f};
  for (int j = beg; j < end; ++j) {
    int s = csr[j];  // block-uniform -> scalar load
    float4 v = ((const float4*)(x + (size_t)s * IN_DIM))[t];
    acc.x += v.x; acc.y += v.y; acc.z += v.z; acc.w += v.w;
  }
  float inv = 1.0f / (float)max(end - beg, 1);
  float4 b = ((const float4*)(x + (size_t)i * IN_DIM))[t];
  ushort4 pa = {f2bf(acc.x * inv), f2bf(acc.y * inv), f2bf(acc.z * inv), f2bf(acc.w * inv)};
  ushort4 pb = {f2bf(b.x), f2bf(b.y), f2bf(b.z), f2bf(b.w)};
  unsigned short* row = A1 + (size_t)i * 2048;
  ((ushort4*)row)[t] = pa;           // cols 0..1023  = mean
  ((ushort4*)(row + 1024))[t] = pb;  // cols 1024..2047 = x
}

// ---------------- weight converts (fp32 -> bf16, concatenated layouts) ----------------
// w1cat [4096][2048]: row n = [W1_l row n | W1_r row n]
__global__ void conv_w1_kernel(const float* __restrict__ Wl, const float* __restrict__ Wr,
                               unsigned short* __restrict__ w1cat) {
  int g = blockIdx.x * 256 + threadIdx.x;  // float4 groups: 4096*512
  int n = g >> 9;
  int kg = g & 511;
  const float* s = (kg < 256) ? (Wl + (size_t)n * 1024 + kg * 4)
                              : (Wr + (size_t)n * 1024 + (kg - 256) * 4);
  float4 v = *(const float4*)s;
  ushort4 p = {f2bf(v.x), f2bf(v.y), f2bf(v.z), f2bf(v.w)};
  ((ushort4*)w1cat)[g] = p;
}

// w2cat [512][4096]: rows 0..255 = W2_l, rows 256..511 = W2_r
__global__ void conv_w2_kernel(const float* __restrict__ Wl, const float* __restrict__ Wr,
                               unsigned short* __restrict__ w2cat) {
  int g = blockIdx.x * 256 + threadIdx.x;  // float4 groups: 512*1024
  int n = g >> 10;
  int kg = g & 1023;
  const float* s = (n < 256) ? (Wl + (size_t)n * 4096 + kg * 4)
                             : (Wr + (size_t)(n - 256) * 4096 + kg * 4);
  float4 v = *(const float4*)s;
  ushort4 p = {f2bf(v.x), f2bf(v.y), f2bf(v.z), f2bf(v.w)};
  ((ushort4*)w2cat)[g] = p;
}

// ---------------- bf16 MFMA GEMM: C[M_PAD,N] = A[M_PAD,K] * Bt[N,K]^T ----------------
// BN = 128 fixed; BM in {64,128}; 4 waves in 2x2 arrangement.
// LDS tiles row-major [rows][32] bf16 with XOR slot swizzle: slot(q,r) = q ^ ((r>>1)&3)
// so ds_read_b128 lands at <=2-way bank aliasing (free) while global_load_lds keeps its
// mandatory contiguous lane order (source chunk is swizzled instead).
template <int BM, int K, int N, bool EPI_RELU_BF16>
__global__ __launch_bounds__(256) void gemm_kernel(const unsigned short* __restrict__ A,
                                                   const unsigned short* __restrict__ Bt,
                                                   const float* __restrict__ bias,
                                                   void* __restrict__ Cout) {
  constexpr int BN = 128;
  constexpr int MI = BM / 32;  // 16-row tiles per wave (m)
  constexpr int NI = 4;        // 16-col tiles per wave (n)
  constexpr int SA = BM / 64;  // A staging segments per wave (1024B each)
  constexpr int SB = BN / 64;
  __shared__ unsigned short Asm[BM * 32];
  __shared__ unsigned short Bsm[BN * 32];

  const int tid = threadIdx.x;
  const int lane = tid & 63;
  const int wave = tid >> 6;
  const int quad = lane >> 4;
  const int l16 = lane & 15;
  const int wm = (wave & 1) * (BM / 2);
  const int wn = (wave >> 1) * 64;
  const long tm0 = (long)blockIdx.x * BM;
  const long tn0 = (long)blockIdx.y * BN;

  f32x4 acc[MI][NI];
#pragma unroll
  for (int i = 0; i < MI; ++i)
#pragma unroll
    for (int j = 0; j < NI; ++j) acc[i][j] = (f32x4){0.f, 0.f, 0.f, 0.f};

  // staging descriptors: chunk c -> row r = c>>2, slot = c&3, source chunk g = slot^((r>>1)&3)
  const unsigned short* aSrc[SA];
  unsigned short* aDst[SA];
  const unsigned short* bSrc[SB];
  unsigned short* bDst[SB];
#pragma unroll
  for (int s = 0; s < SA; ++s) {
    int c = s * 256 + wave * 64 + lane;
    int r = c >> 2;
    int g = (c & 3) ^ ((r >> 1) & 3);
    aSrc[s] = A + (size_t)(tm0 + r) * K + g * 8;
    aDst[s] = Asm + s * 2048 + wave * 512;  // wave-uniform base
  }
#pragma unroll
  for (int s = 0; s < SB; ++s) {
    int c = s * 256 + wave * 64 + lane;
    int r = c >> 2;
    int g = (c & 3) ^ ((r >> 1) & 3);
    bSrc[s] = Bt + (size_t)(tn0 + r) * K + g * 8;
    bDst[s] = Bsm + s * 2048 + wave * 512;
  }

  const int srd = quad ^ ((l16 >> 1) & 3);  // read-slot swizzle (row bits 1..2 == l16 bits 1..2)

  for (int k0 = 0; k0 < K; k0 += 32) {
#pragma unroll
    for (int s = 0; s < SA; ++s) ld_lds16(aSrc[s] + k0, aDst[s]);
#pragma unroll
    for (int s = 0; s < SB; ++s) ld_lds16(bSrc[s] + k0, bDst[s]);
    __syncthreads();  // drains vmcnt -> LDS tiles complete

    bf16x8 af[MI], bv[NI];
#pragma unroll
    for (int i = 0; i < MI; ++i) {
      int ra = wm + i * 16 + l16;
      af[i] = *(const bf16x8*)(Asm + ra * 32 + srd * 8);
    }
#pragma unroll
    for (int j = 0; j < NI; ++j) {
      int rb = wn + j * 16 + l16;
      bv[j] = *(const bf16x8*)(Bsm + rb * 32 + srd * 8);
    }
#pragma unroll
    for (int i = 0; i < MI; ++i)
#pragma unroll
      for (int j = 0; j < NI; ++j)
        acc[i][j] = __builtin_amdgcn_mfma_f32_16x16x32_bf16(af[i], bv[j], acc[i][j], 0, 0, 0);
    __syncthreads();  // LDS reads done before next stage overwrites
  }

  // epilogue: C/D layout col = lane&15, row = quad*4 + reg
  if (EPI_RELU_BF16) {
    unsigned short* C = (unsigned short*)Cout;
#pragma unroll
    for (int i = 0; i < MI; ++i) {
      long m0 = tm0 + wm + i * 16 + quad * 4;
#pragma unroll
      for (int j = 0; j < NI; ++j) {
        int n = (int)tn0 + wn + j * 16 + l16;
        float bvs = bias[n];
#pragma unroll
        for (int r = 0; r < 4; ++r) {
          float v = acc[i][j][r] + bvs;
          v = fmaxf(v, 0.0f);
          C[(size_t)(m0 + r) * N + n] = f2bf(v);
        }
      }
    }
  } else {
    float* C = (float*)Cout;
#pragma unroll
    for (int i = 0; i < MI; ++i) {
      long m0 = tm0 + wm + i * 16 + quad * 4;
#pragma unroll
      for (int j = 0; j < NI; ++j) {
        int n = (int)tn0 + wn + j * 16 + l16;
#pragma unroll
        for (int r = 0; r < 4; ++r) C[(size_t)(m0 + r) * N + n] = acc[i][j][r];
      }
    }
  }
}

// ---------------- layer-2 gather + bias + p_r + log_softmax (fused) ----------------
__global__ __launch_bounds__(256) void gather2_final_kernel(const float* __restrict__ C2,
                                                            const int* __restrict__ offs,
                                                            const int* __restrict__ csr,
                                                            const float* __restrict__ b2,
                                                            float* __restrict__ out) {
  int i = blockIdx.x;
  int t = threadIdx.x;  // 0..255
  int beg = offs[i], end = offs[i + 1];
  float acc = 0.f;
  for (int j = beg; j < end; ++j) {
    int s = csr[j];  // block-uniform
    acc += C2[(size_t)s * 512 + t];
  }
  float inv = 1.0f / (float)max(end - beg, 1);
  float v = acc * inv + b2[t] + C2[(size_t)i * 512 + 256 + t];

  __shared__ float sm[4], ss[4];
  int w = t >> 6;
  float m = v;
#pragma unroll
  for (int o = 32; o > 0; o >>= 1) m = fmaxf(m, __shfl_xor(m, o, 64));
  if ((t & 63) == 0) sm[w] = m;
  __syncthreads();
  m = fmaxf(fmaxf(sm[0], sm[1]), fmaxf(sm[2], sm[3]));

  float e = __expf(v - m);
  float s = e;
#pragma unroll
  for (int o = 32; o > 0; o >>= 1) s += __shfl_xor(s, o, 64);
  if ((t & 63) == 0) ss[w] = s;
  __syncthreads();
  s = ss[0] + ss[1] + ss[2] + ss[3];

  out[(size_t)i * OUTD + t] = v - m - logf(s);
}

// ---------------- workspace layout (bytes) ----------------
// A1    [10112][2048] bf16 = 41,418,752  (later reused as C2 [10112][512] f32)
// w1cat [4096][2048] bf16  = 16,777,216
// h_b   [10112][4096] bf16 = 82,837,504
// w2cat [512][4096] bf16   =  4,194,304
// deg / offs / fill / csr  = ints, ~440 KB
static constexpr size_t OFF_A1 = 0;
static constexpr size_t OFF_W1 = OFF_A1 + (size_t)M_PAD * 2048 * 2;
static constexpr size_t OFF_HB = OFF_W1 + (size_t)HID * 2048 * 2;
static constexpr size_t OFF_W2 = OFF_HB + (size_t)M_PAD * HID * 2;
static constexpr size_t OFF_DEG = OFF_W2 + (size_t)512 * HID * 2;
static constexpr size_t OFF_OFFS = OFF_DEG + (size_t)NN * 4;
static constexpr size_t OFF_FILL = OFF_OFFS + (size_t)(NN + 4) * 4;
static constexpr size_t OFF_CSR = OFF_FILL + (size_t)NN * 4;

extern "C" void kernel_launch(void* const* d_in, const int* in_sizes, int n_in,
                              void* d_out, int out_size, void* d_ws, size_t ws_size,
                              hipStream_t stream) {
  const float* x = (const float*)d_in[0];
  const int* ei = (const int*)d_in[1];
  const int* src = ei;
  const int* dst = ei + NE;
  const float* W1_l = (const float*)d_in[2];
  const float* b1_l = (const float*)d_in[3];
  const float* W1_r = (const float*)d_in[4];
  const float* W2_l = (const float*)d_in[5];
  const float* b2_l = (const float*)d_in[6];
  const float* W2_r = (const float*)d_in[7];
  float* out = (float*)d_out;

  char* ws = (char*)d_ws;
  unsigned short* A1 = (unsigned short*)(ws + OFF_A1);
  unsigned short* w1cat = (unsigned short*)(ws + OFF_W1);
  unsigned short* h_b = (unsigned short*)(ws + OFF_HB);
  unsigned short* w2cat = (unsigned short*)(ws + OFF_W2);
  int* deg = (int*)(ws + OFF_DEG);
  int* offs = (int*)(ws + OFF_OFFS);
  int* fill = (int*)(ws + OFF_FILL);
  int* csr = (int*)(ws + OFF_CSR);
  float* C2 = (float*)(ws + OFF_A1);  // alias: A1 dead after gemm1

  // zero counters + A1 pad rows (ws is poisoned 0xAA before every call)
  hipMemsetAsync(deg, 0, (size_t)NN * 4, stream);
  hipMemsetAsync(fill, 0, (size_t)NN * 4, stream);
  hipMemsetAsync(A1 + (size_t)NN * 2048, 0, (size_t)(M_PAD - NN) * 2048 * 2, stream);

  // CSR build
  deg_kernel<<<(NE + 255) / 256, 256, 0, stream>>>(dst, deg);
  scan_kernel<<<1, 256, 0, stream>>>(deg, offs);
  bin_kernel<<<(NE + 255) / 256, 256, 0, stream>>>(src, dst, offs, fill, csr);

  // weight converts (independent of CSR)
  conv_w1_kernel<<<(HID * 512) / 256, 256, 0, stream>>>(W1_l, W1_r, w1cat);
  conv_w2_kernel<<<(512 * 1024) / 256, 256, 0, stream>>>(W2_l, W2_r, w2cat);

  // A1 = [mean | x] bf16 via CSR gather (no atomics)
  gather1_kernel<<<NN, 256, 0, stream>>>(x, offs, csr, A1);

  // h = relu(A1 @ w1cat^T + b1)  -> bf16 [10112][4096]
  gemm_kernel<128, 2048, 4096, true>
      <<<dim3(M_PAD / 128, HID / 128), 256, 0, stream>>>(A1, w1cat, b1_l, h_b);
  // C2 = h @ w2cat^T -> f32 [10112][512]  (cols 0..255 = p_l, 256..511 = p_r)
  gemm_kernel<64, 4096, 512, false>
      <<<dim3(M_PAD / 64, 512 / 128), 256, 0, stream>>>(h_b, w2cat, nullptr, C2);

  // mean of p_l over in-edges + bias + p_r, then log_softmax
  gather2_final_kernel<<<NN, 256, 0, stream>>>(C2, offs, csr, b2_l, out);
}

// Round 3
// 514.000 us; speedup vs baseline: 3.1287x; 1.0833x over previous
//
#include <hip/hip_runtime.h>
#include <cstdint>
#include <cstddef>

#define DEVINL __device__ __forceinline__

typedef __bf16 bf16x8 __attribute__((ext_vector_type(8)));
typedef float f32x4 __attribute__((ext_vector_type(4)));

static constexpr int NN = 10000;     // nodes
static constexpr int NE = 80000;     // edges
static constexpr int IN_DIM = 1024;
static constexpr int HID = 4096;
static constexpr int OUTD = 256;
static constexpr int M_PAD = 10112;  // 79*128 (also 158*64)

// fp32 -> bf16 round-nearest-even
DEVINL unsigned short f2bf(float f) {
  unsigned int u = __builtin_bit_cast(unsigned int, f);
  u += 0x7fffu + ((u >> 16) & 1u);
  return (unsigned short)(u >> 16);
}

// async global->LDS, 16B per lane; LDS dest is wave-uniform base + lane*16
DEVINL void ld_lds16(const void* g, void* l) {
  __builtin_amdgcn_global_load_lds(
      (const __attribute__((address_space(1))) unsigned int*)g,
      (__attribute__((address_space(3))) unsigned int*)l, 16, 0, 0);
}

// ---------------- CSR build: degree count ----------------
__global__ void deg_kernel(const int* __restrict__ dst, int* __restrict__ deg) {
  int e = blockIdx.x * 256 + threadIdx.x;
  if (e < NE) atomicAdd(&deg[dst[e]], 1);
}

// one-block exclusive scan over NN degrees -> offs[0..NN]
__global__ __launch_bounds__(256) void scan_kernel(const int* __restrict__ deg,
                                                   int* __restrict__ offs) {
  __shared__ int part[256];
  constexpr int NPT = 40;  // 256*40 = 10240 >= NN
  int t = threadIdx.x;
  int base = t * NPT;
  int s = 0;
  for (int j = 0; j < NPT; ++j) {
    int n = base + j;
    s += (n < NN) ? deg[n] : 0;
  }
  part[t] = s;
  __syncthreads();
  for (int o = 1; o < 256; o <<= 1) {  // Hillis-Steele inclusive scan
    int v = (t >= o) ? part[t - o] : 0;
    __syncthreads();
    part[t] += v;
    __syncthreads();
  }
  int pre = (t > 0) ? part[t - 1] : 0;
  for (int j = 0; j < NPT; ++j) {
    int n = base + j;
    if (n < NN) {
      offs[n] = pre;
      pre += deg[n];
    }
  }
  if (t == 255) offs[NN] = part[255];  // == NE
}

// bin edges: csr_src[offs[dst] + fill[dst]++] = src
__global__ void bin_kernel(const int* __restrict__ src, const int* __restrict__ dst,
                           const int* __restrict__ offs, int* __restrict__ fill,
                           int* __restrict__ csr) {
  int e = blockIdx.x * 256 + threadIdx.x;
  if (e < NE) {
    int d = dst[e];
    int p = atomicAdd(&fill[d], 1);
    csr[offs[d] + p] = src[e];
  }
}

// ---------------- layer-1 gather: A1 = [mean_agg(x) | x] in bf16 ----------------
__global__ __launch_bounds__(256) void gather1_kernel(const float* __restrict__ x,
                                                      const int* __restrict__ offs,
                                                      const int* __restrict__ csr,
                                                      unsigned short* __restrict__ A1) {
  int i = blockIdx.x;
  int t = threadIdx.x;  // 256 threads x float4 = 1024 floats
  int beg = offs[i], end = offs[i + 1];
  float4 acc = {0.f, 0.f, 0.f, 0.f};
  for (int j = beg; j < end; ++j) {
    int s = __builtin_amdgcn_readfirstlane(csr[j]);  // block-uniform -> SGPR
    float4 v = ((const float4*)(x + (size_t)s * IN_DIM))[t];
    acc.x += v.x; acc.y += v.y; acc.z += v.z; acc.w += v.w;
  }
  float inv = 1.0f / (float)max(end - beg, 1);
  float4 b = ((const float4*)(x + (size_t)i * IN_DIM))[t];
  ushort4 pa = {f2bf(acc.x * inv), f2bf(acc.y * inv), f2bf(acc.z * inv), f2bf(acc.w * inv)};
  ushort4 pb = {f2bf(b.x), f2bf(b.y), f2bf(b.z), f2bf(b.w)};
  unsigned short* row = A1 + (size_t)i * 2048;
  ((ushort4*)row)[t] = pa;           // cols 0..1023  = mean
  ((ushort4*)(row + 1024))[t] = pb;  // cols 1024..2047 = x
}

// ---------------- weight converts (fp32 -> bf16, concatenated layouts) ----------------
// w1cat [4096][2048]: row n = [W1_l row n | W1_r row n]
__global__ void conv_w1_kernel(const float* __restrict__ Wl, const float* __restrict__ Wr,
                               unsigned short* __restrict__ w1cat) {
  int g = blockIdx.x * 256 + threadIdx.x;  // float4 groups: 4096*512
  int n = g >> 9;
  int kg = g & 511;
  const float* s = (kg < 256) ? (Wl + (size_t)n * 1024 + kg * 4)
                              : (Wr + (size_t)n * 1024 + (kg - 256) * 4);
  float4 v = *(const float4*)s;
  ushort4 p = {f2bf(v.x), f2bf(v.y), f2bf(v.z), f2bf(v.w)};
  ((ushort4*)w1cat)[g] = p;
}

// w2cat [512][4096]: rows 0..255 = W2_l, rows 256..511 = W2_r
__global__ void conv_w2_kernel(const float* __restrict__ Wl, const float* __restrict__ Wr,
                               unsigned short* __restrict__ w2cat) {
  int g = blockIdx.x * 256 + threadIdx.x;  // float4 groups: 512*1024
  int n = g >> 10;
  int kg = g & 1023;
  const float* s = (n < 256) ? (Wl + (size_t)n * 4096 + kg * 4)
                             : (Wr + (size_t)(n - 256) * 4096 + kg * 4);
  float4 v = *(const float4*)s;
  ushort4 p = {f2bf(v.x), f2bf(v.y), f2bf(v.z), f2bf(v.w)};
  ((ushort4*)w2cat)[g] = p;
}

// ---------------- bf16 MFMA GEMM: C[M_PAD,N] = A[M_PAD,K] * Bt[N,K]^T ----------------
// BN = 128 fixed; BM in {64,128}; 4 waves in 2x2 arrangement.
// Grouped block swizzle (Triton-style, GM m-tiles per group) for L2/L3 locality:
// launch a LINEAR grid of NUMM*NUMN blocks; pid -> (pm, pn) below.
// LDS tiles row-major [rows][32] bf16 with XOR slot swizzle: slot(q,r) = q ^ ((r>>1)&3)
// so ds_read_b128 lands at <=2-way bank aliasing (free) while global_load_lds keeps its
// mandatory contiguous lane order (source chunk is swizzled instead).
template <int BM, int K, int N, int NUMM, int NUMN, int GM, bool EPI_RELU_BF16>
__global__ __launch_bounds__(256) void gemm_kernel(const unsigned short* __restrict__ A,
                                                   const unsigned short* __restrict__ Bt,
                                                   const float* __restrict__ bias,
                                                   void* __restrict__ Cout) {
  constexpr int BN = 128;
  constexpr int MI = BM / 32;  // 16-row tiles per wave (m)
  constexpr int NI = 4;        // 16-col tiles per wave (n)
  constexpr int SA = BM / 64;  // A staging segments per wave (1024B each)
  constexpr int SB = BN / 64;
  __shared__ unsigned short Asm[BM * 32];
  __shared__ unsigned short Bsm[BN * 32];

  // grouped swizzle
  constexpr int NPG = GM * NUMN;
  const int pid = blockIdx.x;
  const int gid = pid / NPG;
  const int first_m = gid * GM;
  const int sz = (NUMM - first_m < GM) ? (NUMM - first_m) : GM;
  const int local = pid % NPG;
  const int pm = first_m + local % sz;
  const int pn = local / sz;

  const int tid = threadIdx.x;
  const int lane = tid & 63;
  const int wave = tid >> 6;
  const int quad = lane >> 4;
  const int l16 = lane & 15;
  const int wm = (wave & 1) * (BM / 2);
  const int wn = (wave >> 1) * 64;
  const long tm0 = (long)pm * BM;
  const long tn0 = (long)pn * BN;

  f32x4 acc[MI][NI];
#pragma unroll
  for (int i = 0; i < MI; ++i)
#pragma unroll
    for (int j = 0; j < NI; ++j) acc[i][j] = (f32x4){0.f, 0.f, 0.f, 0.f};

  // staging descriptors: chunk c -> row r = c>>2, slot = c&3, source chunk g = slot^((r>>1)&3)
  const unsigned short* aSrc[SA];
  unsigned short* aDst[SA];
  const unsigned short* bSrc[SB];
  unsigned short* bDst[SB];
#pragma unroll
  for (int s = 0; s < SA; ++s) {
    int c = s * 256 + wave * 64 + lane;
    int r = c >> 2;
    int g = (c & 3) ^ ((r >> 1) & 3);
    aSrc[s] = A + (size_t)(tm0 + r) * K + g * 8;
    aDst[s] = Asm + s * 2048 + wave * 512;  // wave-uniform base
  }
#pragma unroll
  for (int s = 0; s < SB; ++s) {
    int c = s * 256 + wave * 64 + lane;
    int r = c >> 2;
    int g = (c & 3) ^ ((r >> 1) & 3);
    bSrc[s] = Bt + (size_t)(tn0 + r) * K + g * 8;
    bDst[s] = Bsm + s * 2048 + wave * 512;
  }

  const int srd = quad ^ ((l16 >> 1) & 3);  // read-slot swizzle (row bits 1..2 == l16 bits 1..2)

  for (int k0 = 0; k0 < K; k0 += 32) {
#pragma unroll
    for (int s = 0; s < SA; ++s) ld_lds16(aSrc[s] + k0, aDst[s]);
#pragma unroll
    for (int s = 0; s < SB; ++s) ld_lds16(bSrc[s] + k0, bDst[s]);
    __syncthreads();  // drains vmcnt -> LDS tiles complete

    bf16x8 af[MI], bv[NI];
#pragma unroll
    for (int i = 0; i < MI; ++i) {
      int ra = wm + i * 16 + l16;
      af[i] = *(const bf16x8*)(Asm + ra * 32 + srd * 8);
    }
#pragma unroll
    for (int j = 0; j < NI; ++j) {
      int rb = wn + j * 16 + l16;
      bv[j] = *(const bf16x8*)(Bsm + rb * 32 + srd * 8);
    }
#pragma unroll
    for (int i = 0; i < MI; ++i)
#pragma unroll
      for (int j = 0; j < NI; ++j)
        acc[i][j] = __builtin_amdgcn_mfma_f32_16x16x32_bf16(af[i], bv[j], acc[i][j], 0, 0, 0);
    __syncthreads();  // LDS reads done before next stage overwrites
  }

  // epilogue: C/D layout col = lane&15, row = quad*4 + reg
  if (EPI_RELU_BF16) {
    unsigned short* C = (unsigned short*)Cout;
#pragma unroll
    for (int i = 0; i < MI; ++i) {
      long m0 = tm0 + wm + i * 16 + quad * 4;
#pragma unroll
      for (int j = 0; j < NI; ++j) {
        int n = (int)tn0 + wn + j * 16 + l16;
        float bvs = bias[n];
#pragma unroll
        for (int r = 0; r < 4; ++r) {
          float v = acc[i][j][r] + bvs;
          v = fmaxf(v, 0.0f);
          C[(size_t)(m0 + r) * N + n] = f2bf(v);
        }
      }
    }
  } else {
    float* C = (float*)Cout;
#pragma unroll
    for (int i = 0; i < MI; ++i) {
      long m0 = tm0 + wm + i * 16 + quad * 4;
#pragma unroll
      for (int j = 0; j < NI; ++j) {
        int n = (int)tn0 + wn + j * 16 + l16;
#pragma unroll
        for (int r = 0; r < 4; ++r) C[(size_t)(m0 + r) * N + n] = acc[i][j][r];
      }
    }
  }
}

// ---------------- layer-2 gather + bias + p_r + log_softmax (fused) ----------------
__global__ __launch_bounds__(256) void gather2_final_kernel(const float* __restrict__ C2,
                                                            const int* __restrict__ offs,
                                                            const int* __restrict__ csr,
                                                            const float* __restrict__ b2,
                                                            float* __restrict__ out) {
  int i = blockIdx.x;
  int t = threadIdx.x;  // 0..255
  int beg = offs[i], end = offs[i + 1];
  float acc = 0.f;
  for (int j = beg; j < end; ++j) {
    int s = __builtin_amdgcn_readfirstlane(csr[j]);  // block-uniform -> SGPR
    acc += C2[(size_t)s * 512 + t];
  }
  float inv = 1.0f / (float)max(end - beg, 1);
  float v = acc * inv + b2[t] + C2[(size_t)i * 512 + 256 + t];

  __shared__ float sm[4], ss[4];
  int w = t >> 6;
  float m = v;
#pragma unroll
  for (int o = 32; o > 0; o >>= 1) m = fmaxf(m, __shfl_xor(m, o, 64));
  if ((t & 63) == 0) sm[w] = m;
  __syncthreads();
  m = fmaxf(fmaxf(sm[0], sm[1]), fmaxf(sm[2], sm[3]));

  float e = __expf(v - m);
  float s = e;
#pragma unroll
  for (int o = 32; o > 0; o >>= 1) s += __shfl_xor(s, o, 64);
  if ((t & 63) == 0) ss[w] = s;
  __syncthreads();
  s = ss[0] + ss[1] + ss[2] + ss[3];

  out[(size_t)i * OUTD + t] = v - m - logf(s);
}

// ---------------- workspace layout (bytes) ----------------
// A1    [10112][2048] bf16 = 41,418,752  (later reused as C2 [10112][512] f32)
// w1cat [4096][2048] bf16  = 16,777,216
// h_b   [10112][4096] bf16 = 82,837,504
// w2cat [512][4096] bf16   =  4,194,304
// deg / offs / fill / csr  = ints, ~440 KB
static constexpr size_t OFF_A1 = 0;
static constexpr size_t OFF_W1 = OFF_A1 + (size_t)M_PAD * 2048 * 2;
static constexpr size_t OFF_HB = OFF_W1 + (size_t)HID * 2048 * 2;
static constexpr size_t OFF_W2 = OFF_HB + (size_t)M_PAD * HID * 2;
static constexpr size_t OFF_DEG = OFF_W2 + (size_t)512 * HID * 2;
static constexpr size_t OFF_OFFS = OFF_DEG + (size_t)NN * 4;
static constexpr size_t OFF_FILL = OFF_OFFS + (size_t)(NN + 4) * 4;
static constexpr size_t OFF_CSR = OFF_FILL + (size_t)NN * 4;

extern "C" void kernel_launch(void* const* d_in, const int* in_sizes, int n_in,
                              void* d_out, int out_size, void* d_ws, size_t ws_size,
                              hipStream_t stream) {
  const float* x = (const float*)d_in[0];
  const int* ei = (const int*)d_in[1];
  const int* src = ei;
  const int* dst = ei + NE;
  const float* W1_l = (const float*)d_in[2];
  const float* b1_l = (const float*)d_in[3];
  const float* W1_r = (const float*)d_in[4];
  const float* W2_l = (const float*)d_in[5];
  const float* b2_l = (const float*)d_in[6];
  const float* W2_r = (const float*)d_in[7];
  float* out = (float*)d_out;

  char* ws = (char*)d_ws;
  unsigned short* A1 = (unsigned short*)(ws + OFF_A1);
  unsigned short* w1cat = (unsigned short*)(ws + OFF_W1);
  unsigned short* h_b = (unsigned short*)(ws + OFF_HB);
  unsigned short* w2cat = (unsigned short*)(ws + OFF_W2);
  int* deg = (int*)(ws + OFF_DEG);
  int* offs = (int*)(ws + OFF_OFFS);
  int* fill = (int*)(ws + OFF_FILL);
  int* csr = (int*)(ws + OFF_CSR);
  float* C2 = (float*)(ws + OFF_A1);  // alias: A1 dead after gemm1

  // zero counters + A1 pad rows (ws is poisoned 0xAA before every call)
  hipMemsetAsync(deg, 0, (size_t)NN * 4, stream);
  hipMemsetAsync(fill, 0, (size_t)NN * 4, stream);
  hipMemsetAsync(A1 + (size_t)NN * 2048, 0, (size_t)(M_PAD - NN) * 2048 * 2, stream);

  // CSR build
  deg_kernel<<<(NE + 255) / 256, 256, 0, stream>>>(dst, deg);
  scan_kernel<<<1, 256, 0, stream>>>(deg, offs);
  bin_kernel<<<(NE + 255) / 256, 256, 0, stream>>>(src, dst, offs, fill, csr);

  // weight converts (independent of CSR)
  conv_w1_kernel<<<(HID * 512) / 256, 256, 0, stream>>>(W1_l, W1_r, w1cat);
  conv_w2_kernel<<<(512 * 1024) / 256, 256, 0, stream>>>(W2_l, W2_r, w2cat);

  // A1 = [mean | x] bf16 via CSR gather (no atomics)
  gather1_kernel<<<NN, 256, 0, stream>>>(x, offs, csr, A1);

  // h = relu(A1 @ w1cat^T + b1)  -> bf16 [10112][4096]; grid linear, GM=32 group swizzle
  gemm_kernel<128, 2048, 4096, 79, 32, 32, true>
      <<<79 * 32, 256, 0, stream>>>(A1, w1cat, b1_l, h_b);
  // C2 = h @ w2cat^T -> f32 [10112][512]  (cols 0..255 = p_l, 256..511 = p_r); GM=64
  gemm_kernel<64, 4096, 512, 158, 4, 64, false>
      <<<158 * 4, 256, 0, stream>>>(h_b, w2cat, nullptr, C2);

  // mean of p_l over in-edges + bias + p_r, then log_softmax
  gather2_final_kernel<<<NN, 256, 0, stream>>>(C2, offs, csr, b2_l, out);
}

// Round 4
// 483.928 us; speedup vs baseline: 3.3231x; 1.0621x over previous
//
#include <hip/hip_runtime.h>
#include <cstdint>
#include <cstddef>

#define DEVINL __device__ __forceinline__

typedef __bf16 bf16x8 __attribute__((ext_vector_type(8)));
typedef float f32x4 __attribute__((ext_vector_type(4)));

static constexpr int NN = 10000;     // nodes
static constexpr int NE = 80000;     // edges
static constexpr int IN_DIM = 1024;
static constexpr int HID = 4096;
static constexpr int OUTD = 256;
static constexpr int M_PAD = 10112;  // 79*128 (also 158*64)

// fp32 -> bf16 round-nearest-even
DEVINL unsigned short f2bf(float f) {
  unsigned int u = __builtin_bit_cast(unsigned int, f);
  u += 0x7fffu + ((u >> 16) & 1u);
  return (unsigned short)(u >> 16);
}
DEVINL float bf2f(unsigned short h) {
  unsigned int u = ((unsigned int)h) << 16;
  return __builtin_bit_cast(float, u);
}

// async global->LDS, 16B per lane; LDS dest is wave-uniform base + lane*16
DEVINL void ld_lds16(const void* g, void* l) {
  __builtin_amdgcn_global_load_lds(
      (const __attribute__((address_space(1))) unsigned int*)g,
      (__attribute__((address_space(3))) unsigned int*)l, 16, 0, 0);
}

// ---------------- fused prep: conv_w1 + conv_w2 + x->bf16 + degree count ----------------
// block ranges: [0,8192) conv_w1 | [8192,10240) conv_w2 | [10240,20240) conv_x | [20240,20553) deg
static constexpr int PREP_B1 = 8192;
static constexpr int PREP_B2 = PREP_B1 + 2048;
static constexpr int PREP_B3 = PREP_B2 + 10000;
static constexpr int PREP_NB = PREP_B3 + 313;

__global__ __launch_bounds__(256) void prep_kernel(
    const float* __restrict__ W1l, const float* __restrict__ W1r,
    const float* __restrict__ W2l, const float* __restrict__ W2r,
    const float* __restrict__ x, const int* __restrict__ dst,
    unsigned short* __restrict__ w1cat, unsigned short* __restrict__ w2cat,
    unsigned short* __restrict__ x_bf, int* __restrict__ deg) {
  int b = blockIdx.x;
  int t = threadIdx.x;
  if (b < PREP_B1) {  // w1cat [4096][2048]: row n = [W1_l row n | W1_r row n]
    int g = b * 256 + t;
    int n = g >> 9;
    int kg = g & 511;
    const float* s = (kg < 256) ? (W1l + (size_t)n * 1024 + kg * 4)
                                : (W1r + (size_t)n * 1024 + (kg - 256) * 4);
    float4 v = *(const float4*)s;
    ushort4 p = {f2bf(v.x), f2bf(v.y), f2bf(v.z), f2bf(v.w)};
    ((ushort4*)w1cat)[g] = p;
  } else if (b < PREP_B2) {  // w2cat [512][4096]: rows 0..255 = W2_l, 256..511 = W2_r
    int g = (b - PREP_B1) * 256 + t;
    int n = g >> 10;
    int kg = g & 1023;
    const float* s = (n < 256) ? (W2l + (size_t)n * 4096 + kg * 4)
                               : (W2r + (size_t)(n - 256) * 4096 + kg * 4);
    float4 v = *(const float4*)s;
    ushort4 p = {f2bf(v.x), f2bf(v.y), f2bf(v.z), f2bf(v.w)};
    ((ushort4*)w2cat)[g] = p;
  } else if (b < PREP_B3) {  // x -> bf16, [10000][1024]
    int g = (b - PREP_B2) * 256 + t;
    int i = g >> 8;
    int kg = g & 255;
    float4 v = ((const float4*)(x + (size_t)i * IN_DIM))[kg];
    ushort4 p = {f2bf(v.x), f2bf(v.y), f2bf(v.z), f2bf(v.w)};
    ((ushort4*)(x_bf + (size_t)i * IN_DIM))[kg] = p;
  } else {  // degree count
    int e = (b - PREP_B3) * 256 + t;
    if (e < NE) atomicAdd(&deg[dst[e]], 1);
  }
}

// one-block exclusive scan over NN degrees -> offs[0..NN]
__global__ __launch_bounds__(256) void scan_kernel(const int* __restrict__ deg,
                                                   int* __restrict__ offs) {
  __shared__ int part[256];
  constexpr int NPT = 40;  // 256*40 = 10240 >= NN
  int t = threadIdx.x;
  int base = t * NPT;
  int s = 0;
  for (int j = 0; j < NPT; ++j) {
    int n = base + j;
    s += (n < NN) ? deg[n] : 0;
  }
  part[t] = s;
  __syncthreads();
  for (int o = 1; o < 256; o <<= 1) {  // Hillis-Steele inclusive scan
    int v = (t >= o) ? part[t - o] : 0;
    __syncthreads();
    part[t] += v;
    __syncthreads();
  }
  int pre = (t > 0) ? part[t - 1] : 0;
  for (int j = 0; j < NPT; ++j) {
    int n = base + j;
    if (n < NN) {
      offs[n] = pre;
      pre += deg[n];
    }
  }
  if (t == 255) offs[NN] = part[255];  // == NE
}

// bin edges: csr_src[offs[dst] + fill[dst]++] = src
__global__ void bin_kernel(const int* __restrict__ src, const int* __restrict__ dst,
                           const int* __restrict__ offs, int* __restrict__ fill,
                           int* __restrict__ csr) {
  int e = blockIdx.x * 256 + threadIdx.x;
  if (e < NE) {
    int d = dst[e];
    int p = atomicAdd(&fill[d], 1);
    csr[offs[d] + p] = src[e];
  }
}

// ---------------- layer-1 gather (bf16 source): A1 = [mean_agg(x) | x] ----------------
__global__ __launch_bounds__(256) void gather1_kernel(const unsigned short* __restrict__ x_bf,
                                                      const int* __restrict__ offs,
                                                      const int* __restrict__ csr,
                                                      unsigned short* __restrict__ A1) {
  int i = blockIdx.x;
  int t = threadIdx.x;  // 256 threads x ushort4 = 1024 bf16 = one row
  int beg = offs[i], end = offs[i + 1];
  float4 acc = {0.f, 0.f, 0.f, 0.f};
  for (int j = beg; j < end; ++j) {
    int s = __builtin_amdgcn_readfirstlane(csr[j]);  // block-uniform -> SGPR
    ushort4 u = ((const ushort4*)(x_bf + (size_t)s * IN_DIM))[t];
    acc.x += bf2f(u.x); acc.y += bf2f(u.y); acc.z += bf2f(u.z); acc.w += bf2f(u.w);
  }
  float inv = 1.0f / (float)max(end - beg, 1);
  ushort4 ub = ((const ushort4*)(x_bf + (size_t)i * IN_DIM))[t];
  ushort4 pa = {f2bf(acc.x * inv), f2bf(acc.y * inv), f2bf(acc.z * inv), f2bf(acc.w * inv)};
  unsigned short* row = A1 + (size_t)i * 2048;
  ((ushort4*)row)[t] = pa;           // cols 0..1023  = mean
  ((ushort4*)(row + 1024))[t] = ub;  // cols 1024..2047 = x
}

// ---------------- bf16 MFMA GEMM: C[M_PAD,N] = A[M_PAD,K] * Bt[N,K]^T ----------------
// BN = 128 fixed; BM in {64,128}; 4 waves in 2x2 arrangement.
// Grouped block swizzle (Triton-style, GM m-tiles per group) for L2/L3 locality.
// EPI 1: C0 = bf16 [M][N], relu(acc + bias)   (layer 1)
// EPI 2: split: n<256 -> C0 bf16 [M][256] (p_l), n>=256 -> C1 f32 [M][256] (p_r)
template <int BM, int K, int N, int NUMM, int NUMN, int GM, int EPI>
__global__ __launch_bounds__(256) void gemm_kernel(const unsigned short* __restrict__ A,
                                                   const unsigned short* __restrict__ Bt,
                                                   const float* __restrict__ bias,
                                                   void* __restrict__ C0out,
                                                   void* __restrict__ C1out) {
  constexpr int BN = 128;
  constexpr int MI = BM / 32;  // 16-row tiles per wave (m)
  constexpr int NI = 4;        // 16-col tiles per wave (n)
  constexpr int SA = BM / 64;  // A staging segments per wave (1024B each)
  constexpr int SB = BN / 64;
  __shared__ unsigned short Asm[BM * 32];
  __shared__ unsigned short Bsm[BN * 32];

  // grouped swizzle
  constexpr int NPG = GM * NUMN;
  const int pid = blockIdx.x;
  const int gid = pid / NPG;
  const int first_m = gid * GM;
  const int sz = (NUMM - first_m < GM) ? (NUMM - first_m) : GM;
  const int local = pid % NPG;
  const int pm = first_m + local % sz;
  const int pn = local / sz;

  const int tid = threadIdx.x;
  const int lane = tid & 63;
  const int wave = tid >> 6;
  const int quad = lane >> 4;
  const int l16 = lane & 15;
  const int wm = (wave & 1) * (BM / 2);
  const int wn = (wave >> 1) * 64;
  const long tm0 = (long)pm * BM;
  const long tn0 = (long)pn * BN;

  f32x4 acc[MI][NI];
#pragma unroll
  for (int i = 0; i < MI; ++i)
#pragma unroll
    for (int j = 0; j < NI; ++j) acc[i][j] = (f32x4){0.f, 0.f, 0.f, 0.f};

  // staging descriptors: chunk c -> row r = c>>2, slot = c&3, source chunk g = slot^((r>>1)&3)
  const unsigned short* aSrc[SA];
  unsigned short* aDst[SA];
  const unsigned short* bSrc[SB];
  unsigned short* bDst[SB];
#pragma unroll
  for (int s = 0; s < SA; ++s) {
    int c = s * 256 + wave * 64 + lane;
    int r = c >> 2;
    int g = (c & 3) ^ ((r >> 1) & 3);
    aSrc[s] = A + (size_t)(tm0 + r) * K + g * 8;
    aDst[s] = Asm + s * 2048 + wave * 512;  // wave-uniform base
  }
#pragma unroll
  for (int s = 0; s < SB; ++s) {
    int c = s * 256 + wave * 64 + lane;
    int r = c >> 2;
    int g = (c & 3) ^ ((r >> 1) & 3);
    bSrc[s] = Bt + (size_t)(tn0 + r) * K + g * 8;
    bDst[s] = Bsm + s * 2048 + wave * 512;
  }

  const int srd = quad ^ ((l16 >> 1) & 3);  // read-slot swizzle

  for (int k0 = 0; k0 < K; k0 += 32) {
#pragma unroll
    for (int s = 0; s < SA; ++s) ld_lds16(aSrc[s] + k0, aDst[s]);
#pragma unroll
    for (int s = 0; s < SB; ++s) ld_lds16(bSrc[s] + k0, bDst[s]);
    __syncthreads();  // drains vmcnt -> LDS tiles complete

    bf16x8 af[MI], bv[NI];
#pragma unroll
    for (int i = 0; i < MI; ++i) {
      int ra = wm + i * 16 + l16;
      af[i] = *(const bf16x8*)(Asm + ra * 32 + srd * 8);
    }
#pragma unroll
    for (int j = 0; j < NI; ++j) {
      int rb = wn + j * 16 + l16;
      bv[j] = *(const bf16x8*)(Bsm + rb * 32 + srd * 8);
    }
#pragma unroll
    for (int i = 0; i < MI; ++i)
#pragma unroll
      for (int j = 0; j < NI; ++j)
        acc[i][j] = __builtin_amdgcn_mfma_f32_16x16x32_bf16(af[i], bv[j], acc[i][j], 0, 0, 0);
    __syncthreads();  // LDS reads done before next stage overwrites
  }

  // epilogue: C/D layout col = lane&15, row = quad*4 + reg
  if (EPI == 1) {
    unsigned short* C = (unsigned short*)C0out;
#pragma unroll
    for (int i = 0; i < MI; ++i) {
      long m0 = tm0 + wm + i * 16 + quad * 4;
#pragma unroll
      for (int j = 0; j < NI; ++j) {
        int n = (int)tn0 + wn + j * 16 + l16;
        float bvs = bias[n];
#pragma unroll
        for (int r = 0; r < 4; ++r) {
          float v = acc[i][j][r] + bvs;
          v = fmaxf(v, 0.0f);
          C[(size_t)(m0 + r) * N + n] = f2bf(v);
        }
      }
    }
  } else {  // EPI == 2: split p_l (bf16) / p_r (f32), both stride 256
    unsigned short* PL = (unsigned short*)C0out;
    float* PR = (float*)C1out;
#pragma unroll
    for (int i = 0; i < MI; ++i) {
      long m0 = tm0 + wm + i * 16 + quad * 4;
#pragma unroll
      for (int j = 0; j < NI; ++j) {
        int n = (int)tn0 + wn + j * 16 + l16;  // 16-aligned per (j): branch is uniform
        if (n < 256) {
#pragma unroll
          for (int r = 0; r < 4; ++r) PL[(size_t)(m0 + r) * 256 + n] = f2bf(acc[i][j][r]);
        } else {
#pragma unroll
          for (int r = 0; r < 4; ++r) PR[(size_t)(m0 + r) * 256 + (n - 256)] = acc[i][j][r];
        }
      }
    }
  }
}

// ---------------- layer-2 gather + bias + p_r + log_softmax (fused) ----------------
// 128 threads/block, thread t owns cols {2t, 2t+1}; p_l read as packed 2xbf16.
__global__ __launch_bounds__(128) void gather2_final_kernel(const unsigned short* __restrict__ pl,
                                                            const float* __restrict__ pr,
                                                            const int* __restrict__ offs,
                                                            const int* __restrict__ csr,
                                                            const float* __restrict__ b2,
                                                            float* __restrict__ out) {
  int i = blockIdx.x;
  int t = threadIdx.x;  // 0..127
  int beg = offs[i], end = offs[i + 1];
  float a0 = 0.f, a1 = 0.f;
  for (int j = beg; j < end; ++j) {
    int s = __builtin_amdgcn_readfirstlane(csr[j]);  // block-uniform -> SGPR
    unsigned int u = ((const unsigned int*)(pl + (size_t)s * 256))[t];
    a0 += bf2f((unsigned short)(u & 0xffffu));
    a1 += bf2f((unsigned short)(u >> 16));
  }
  float inv = 1.0f / (float)max(end - beg, 1);
  float2 bv = ((const float2*)b2)[t];
  float2 pv = ((const float2*)(pr + (size_t)i * 256))[t];
  float v0 = a0 * inv + bv.x + pv.x;
  float v1 = a1 * inv + bv.y + pv.y;

  __shared__ float sm[2], ss[2];
  int w = t >> 6;
  float m = fmaxf(v0, v1);
#pragma unroll
  for (int o = 32; o > 0; o >>= 1) m = fmaxf(m, __shfl_xor(m, o, 64));
  if ((t & 63) == 0) sm[w] = m;
  __syncthreads();
  m = fmaxf(sm[0], sm[1]);

  float s = __expf(v0 - m) + __expf(v1 - m);
#pragma unroll
  for (int o = 32; o > 0; o >>= 1) s += __shfl_xor(s, o, 64);
  if ((t & 63) == 0) ss[w] = s;
  __syncthreads();
  float ls = logf(ss[0] + ss[1]);

  float2 o2 = {v0 - m - ls, v1 - m - ls};
  ((float2*)(out + (size_t)i * OUTD))[t] = o2;
}

// ---------------- workspace layout (bytes) ----------------
// A1    [10112][2048] bf16 = 41,418,752  (later reused: pl [10112][256] bf16 + pr [10112][256] f32)
// w1cat [4096][2048] bf16  = 16,777,216
// h_b   [10112][4096] bf16 = 82,837,504  (tail 20,480,000 B aliases x_bf [10000][1024] bf16)
// w2cat [512][4096] bf16   =  4,194,304
// deg / offs / fill / csr  = ints, ~440 KB
static constexpr size_t OFF_A1 = 0;
static constexpr size_t OFF_W1 = OFF_A1 + (size_t)M_PAD * 2048 * 2;
static constexpr size_t OFF_HB = OFF_W1 + (size_t)HID * 2048 * 2;
static constexpr size_t OFF_W2 = OFF_HB + (size_t)M_PAD * HID * 2;
static constexpr size_t OFF_XBF = OFF_W2 - (size_t)NN * IN_DIM * 2;  // tail of h_b
static constexpr size_t OFF_DEG = OFF_W2 + (size_t)512 * HID * 2;
static constexpr size_t OFF_OFFS = OFF_DEG + (size_t)NN * 4;
static constexpr size_t OFF_FILL = OFF_OFFS + (size_t)(NN + 4) * 4;
static constexpr size_t OFF_CSR = OFF_FILL + (size_t)NN * 4;
static constexpr size_t OFF_PL = OFF_A1;                              // alias: A1 dead after gemm1
static constexpr size_t OFF_PR = OFF_PL + (size_t)M_PAD * 256 * 2;

extern "C" void kernel_launch(void* const* d_in, const int* in_sizes, int n_in,
                              void* d_out, int out_size, void* d_ws, size_t ws_size,
                              hipStream_t stream) {
  const float* x = (const float*)d_in[0];
  const int* ei = (const int*)d_in[1];
  const int* src = ei;
  const int* dst = ei + NE;
  const float* W1_l = (const float*)d_in[2];
  const float* b1_l = (const float*)d_in[3];
  const float* W1_r = (const float*)d_in[4];
  const float* W2_l = (const float*)d_in[5];
  const float* b2_l = (const float*)d_in[6];
  const float* W2_r = (const float*)d_in[7];
  float* out = (float*)d_out;

  char* ws = (char*)d_ws;
  unsigned short* A1 = (unsigned short*)(ws + OFF_A1);
  unsigned short* w1cat = (unsigned short*)(ws + OFF_W1);
  unsigned short* h_b = (unsigned short*)(ws + OFF_HB);
  unsigned short* x_bf = (unsigned short*)(ws + OFF_XBF);
  unsigned short* w2cat = (unsigned short*)(ws + OFF_W2);
  int* deg = (int*)(ws + OFF_DEG);
  int* offs = (int*)(ws + OFF_OFFS);
  int* fill = (int*)(ws + OFF_FILL);
  int* csr = (int*)(ws + OFF_CSR);
  unsigned short* pl = (unsigned short*)(ws + OFF_PL);
  float* pr = (float*)(ws + OFF_PR);

  // zero counters + A1 pad rows (ws is poisoned 0xAA before every call)
  hipMemsetAsync(deg, 0, (size_t)NN * 4, stream);
  hipMemsetAsync(fill, 0, (size_t)NN * 4, stream);
  hipMemsetAsync(A1 + (size_t)NN * 2048, 0, (size_t)(M_PAD - NN) * 2048 * 2, stream);

  // fused prep: weight converts + x->bf16 + degree count
  prep_kernel<<<PREP_NB, 256, 0, stream>>>(W1_l, W1_r, W2_l, W2_r, x, dst,
                                           w1cat, w2cat, x_bf, deg);
  scan_kernel<<<1, 256, 0, stream>>>(deg, offs);
  bin_kernel<<<(NE + 255) / 256, 256, 0, stream>>>(src, dst, offs, fill, csr);

  // A1 = [mean | x] bf16 via CSR gather from bf16 x (no atomics)
  gather1_kernel<<<NN, 256, 0, stream>>>(x_bf, offs, csr, A1);

  // h = relu(A1 @ w1cat^T + b1)  -> bf16 [10112][4096]; GM=32 group swizzle
  gemm_kernel<128, 2048, 4096, 79, 32, 32, 1>
      <<<79 * 32, 256, 0, stream>>>(A1, w1cat, b1_l, h_b, nullptr);
  // [p_l | p_r] = h @ w2cat^T -> p_l bf16 [10112][256], p_r f32 [10112][256]; GM=64
  gemm_kernel<64, 4096, 512, 158, 4, 64, 2>
      <<<158 * 4, 256, 0, stream>>>(h_b, w2cat, nullptr, pl, pr);

  // mean of p_l over in-edges + bias + p_r, then log_softmax
  gather2_final_kernel<<<NN, 128, 0, stream>>>(pl, pr, offs, csr, b2_l, out);
}

// Round 5
// 446.634 us; speedup vs baseline: 3.6006x; 1.0835x over previous
//
#include <hip/hip_runtime.h>
#include <cstdint>
#include <cstddef>

#define DEVINL __device__ __forceinline__

typedef __bf16 bf16x8 __attribute__((ext_vector_type(8)));
typedef float f32x4 __attribute__((ext_vector_type(4)));

static constexpr int NN = 10000;     // nodes
static constexpr int NE = 80000;     // edges
static constexpr int IN_DIM = 1024;
static constexpr int HID = 4096;
static constexpr int OUTD = 256;
static constexpr int M_PAD = 10112;  // 79*128 (also 158*64)

// fp32 -> bf16 round-nearest-even
DEVINL unsigned short f2bf(float f) {
  unsigned int u = __builtin_bit_cast(unsigned int, f);
  u += 0x7fffu + ((u >> 16) & 1u);
  return (unsigned short)(u >> 16);
}
DEVINL float bf2f(unsigned short h) {
  unsigned int u = ((unsigned int)h) << 16;
  return __builtin_bit_cast(float, u);
}

// async global->LDS, 16B per lane; LDS dest is wave-uniform base + lane*16
DEVINL void ld_lds16(const void* g, void* l) {
  __builtin_amdgcn_global_load_lds(
      (const __attribute__((address_space(1))) unsigned int*)g,
      (__attribute__((address_space(3))) unsigned int*)l, 16, 0, 0);
}

// ---------------- fused prep: conv_w1 + conv_w2 + x->bf16 + degree count ----------------
static constexpr int PREP_B1 = 8192;
static constexpr int PREP_B2 = PREP_B1 + 2048;
static constexpr int PREP_B3 = PREP_B2 + 10000;
static constexpr int PREP_NB = PREP_B3 + 313;

__global__ __launch_bounds__(256) void prep_kernel(
    const float* __restrict__ W1l, const float* __restrict__ W1r,
    const float* __restrict__ W2l, const float* __restrict__ W2r,
    const float* __restrict__ x, const int* __restrict__ dst,
    unsigned short* __restrict__ w1cat, unsigned short* __restrict__ w2cat,
    unsigned short* __restrict__ x_bf, int* __restrict__ deg) {
  int b = blockIdx.x;
  int t = threadIdx.x;
  if (b < PREP_B1) {  // w1cat [4096][2048]: row n = [W1_l row n | W1_r row n]
    int g = b * 256 + t;
    int n = g >> 9;
    int kg = g & 511;
    const float* s = (kg < 256) ? (W1l + (size_t)n * 1024 + kg * 4)
                                : (W1r + (size_t)n * 1024 + (kg - 256) * 4);
    float4 v = *(const float4*)s;
    ushort4 p = {f2bf(v.x), f2bf(v.y), f2bf(v.z), f2bf(v.w)};
    ((ushort4*)w1cat)[g] = p;
  } else if (b < PREP_B2) {  // w2cat [512][4096]: rows 0..255 = W2_l, 256..511 = W2_r
    int g = (b - PREP_B1) * 256 + t;
    int n = g >> 10;
    int kg = g & 1023;
    const float* s = (n < 256) ? (W2l + (size_t)n * 4096 + kg * 4)
                               : (W2r + (size_t)(n - 256) * 4096 + kg * 4);
    float4 v = *(const float4*)s;
    ushort4 p = {f2bf(v.x), f2bf(v.y), f2bf(v.z), f2bf(v.w)};
    ((ushort4*)w2cat)[g] = p;
  } else if (b < PREP_B3) {  // x -> bf16, [10000][1024]
    int g = (b - PREP_B2) * 256 + t;
    int i = g >> 8;
    int kg = g & 255;
    float4 v = ((const float4*)(x + (size_t)i * IN_DIM))[kg];
    ushort4 p = {f2bf(v.x), f2bf(v.y), f2bf(v.z), f2bf(v.w)};
    ((ushort4*)(x_bf + (size_t)i * IN_DIM))[kg] = p;
  } else {  // degree count
    int e = (b - PREP_B3) * 256 + t;
    if (e < NE) atomicAdd(&deg[dst[e]], 1);
  }
}

// one-block exclusive scan over NN degrees -> offs[0..NN] and cursor copy cur[]
__global__ __launch_bounds__(256) void scan_kernel(const int* __restrict__ deg,
                                                   int* __restrict__ offs,
                                                   int* __restrict__ cur) {
  __shared__ int part[256];
  constexpr int NPT = 40;  // 256*40 = 10240 >= NN
  int t = threadIdx.x;
  int base = t * NPT;
  int s = 0;
  for (int j = 0; j < NPT; ++j) {
    int n = base + j;
    s += (n < NN) ? deg[n] : 0;
  }
  part[t] = s;
  __syncthreads();
  for (int o = 1; o < 256; o <<= 1) {  // Hillis-Steele inclusive scan
    int v = (t >= o) ? part[t - o] : 0;
    __syncthreads();
    part[t] += v;
    __syncthreads();
  }
  int pre = (t > 0) ? part[t - 1] : 0;
  for (int j = 0; j < NPT; ++j) {
    int n = base + j;
    if (n < NN) {
      offs[n] = pre;
      cur[n] = pre;
      pre += deg[n];
    }
  }
  if (t == 255) offs[NN] = part[255];  // == NE
}

// bin edges: csr[cur[dst]++] = src  (cur pre-seeded with offs by scan)
__global__ void bin_kernel(const int* __restrict__ src, const int* __restrict__ dst,
                           int* __restrict__ cur, int* __restrict__ csr) {
  int e = blockIdx.x * 256 + threadIdx.x;
  if (e < NE) {
    int p = atomicAdd(&cur[dst[e]], 1);
    csr[p] = src[e];
  }
}

// ---------------- layer-1 gather (bf16 source): A1 = [mean_agg(x) | x] ----------------
__global__ __launch_bounds__(256) void gather1_kernel(const unsigned short* __restrict__ x_bf,
                                                      const int* __restrict__ offs,
                                                      const int* __restrict__ csr,
                                                      unsigned short* __restrict__ A1) {
  int i = blockIdx.x;
  int t = threadIdx.x;  // 256 threads x ushort4 = 1024 bf16 = one row
  int beg = offs[i], end = offs[i + 1];
  float4 acc = {0.f, 0.f, 0.f, 0.f};
  for (int j = beg; j < end; ++j) {
    int s = __builtin_amdgcn_readfirstlane(csr[j]);  // block-uniform -> SGPR
    ushort4 u = ((const ushort4*)(x_bf + (size_t)s * IN_DIM))[t];
    acc.x += bf2f(u.x); acc.y += bf2f(u.y); acc.z += bf2f(u.z); acc.w += bf2f(u.w);
  }
  float inv = 1.0f / (float)max(end - beg, 1);
  ushort4 ub = ((const ushort4*)(x_bf + (size_t)i * IN_DIM))[t];
  ushort4 pa = {f2bf(acc.x * inv), f2bf(acc.y * inv), f2bf(acc.z * inv), f2bf(acc.w * inv)};
  unsigned short* row = A1 + (size_t)i * 2048;
  ((ushort4*)row)[t] = pa;           // cols 0..1023  = mean
  ((ushort4*)(row + 1024))[t] = ub;  // cols 1024..2047 = x
}

// ---------------- bf16 MFMA GEMM, BK=64: C[M_PAD,N] = A[M_PAD,K] * Bt[N,K]^T ----------------
// BN = 128 fixed; BM in {64,128}; 4 waves in 2x2 arrangement; K-tile = 64 (half the barriers
// of BK=32 — attacks the per-barrier vmcnt drain, the m97-structure ~20% stall).
// LDS row = 64 bf16 = 128 B = 8 chunks of 16 B. Chunk swizzle: physical chunk p of row r
// holds logical chunk p ^ (r & 7). global_load_lds stays lane-contiguous (source column is
// swizzled); ds_read_b128 at p=(kk*4+quad)^(l16&7) -> 2-way bank aliasing (free).
// EPI 1: C0 = bf16 [M][N], relu(acc + bias)   (layer 1)
// EPI 2: split: n<256 -> C0 bf16 [M][256] (p_l), n>=256 -> C1 f32 [M][256] (p_r)
template <int BM, int K, int N, int NUMM, int NUMN, int GM, int EPI>
__global__ __launch_bounds__(256) void gemm_kernel(const unsigned short* __restrict__ A,
                                                   const unsigned short* __restrict__ Bt,
                                                   const float* __restrict__ bias,
                                                   void* __restrict__ C0out,
                                                   void* __restrict__ C1out) {
  constexpr int BN = 128;
  constexpr int MI = BM / 32;   // 16-row tiles per wave (m)
  constexpr int NI = 4;         // 16-col tiles per wave (n)
  constexpr int SA = BM / 32;   // staging segments (256 threads x 16B each) for A
  constexpr int SB = BN / 32;
  __shared__ unsigned short Asm[BM * 64];
  __shared__ unsigned short Bsm[BN * 64];

  // grouped swizzle
  constexpr int NPG = GM * NUMN;
  const int pid = blockIdx.x;
  const int gid = pid / NPG;
  const int first_m = gid * GM;
  const int sz = (NUMM - first_m < GM) ? (NUMM - first_m) : GM;
  const int local = pid % NPG;
  const int pm = first_m + local % sz;
  const int pn = local / sz;

  const int tid = threadIdx.x;
  const int lane = tid & 63;
  const int wave = tid >> 6;
  const int quad = lane >> 4;
  const int l16 = lane & 15;
  const int wm = (wave & 1) * (BM / 2);
  const int wn = (wave >> 1) * 64;
  const long tm0 = (long)pm * BM;
  const long tn0 = (long)pn * BN;

  f32x4 acc[MI][NI];
#pragma unroll
  for (int i = 0; i < MI; ++i)
#pragma unroll
    for (int j = 0; j < NI; ++j) acc[i][j] = (f32x4){0.f, 0.f, 0.f, 0.f};

  // staging: chunk c = s*256 + tid; row r = c>>3; physical slot = c&7;
  // source logical chunk g = (c&7) ^ (r&7)  -> global col g*8
  const unsigned short* aSrc[SA];
  unsigned short* aDst[SA];
  const unsigned short* bSrc[SB];
  unsigned short* bDst[SB];
#pragma unroll
  for (int s = 0; s < SA; ++s) {
    int c = s * 256 + wave * 64 + lane;
    int r = c >> 3;
    int g = (c & 7) ^ (r & 7);
    aSrc[s] = A + (size_t)(tm0 + r) * K + g * 8;
    aDst[s] = Asm + s * 2048 + wave * 512;  // wave-uniform base
  }
#pragma unroll
  for (int s = 0; s < SB; ++s) {
    int c = s * 256 + wave * 64 + lane;
    int r = c >> 3;
    int g = (c & 7) ^ (r & 7);
    bSrc[s] = Bt + (size_t)(tn0 + r) * K + g * 8;
    bDst[s] = Bsm + s * 2048 + wave * 512;
  }

  const int l7 = l16 & 7;

  for (int k0 = 0; k0 < K; k0 += 64) {
#pragma unroll
    for (int s = 0; s < SA; ++s) ld_lds16(aSrc[s] + k0, aDst[s]);
#pragma unroll
    for (int s = 0; s < SB; ++s) ld_lds16(bSrc[s] + k0, bDst[s]);
    __syncthreads();  // drains vmcnt -> LDS tiles complete

#pragma unroll
    for (int kk = 0; kk < 2; ++kk) {
      const int p = (kk * 4 + quad) ^ l7;  // physical chunk for this frag
      bf16x8 af[MI], bv[NI];
#pragma unroll
      for (int i = 0; i < MI; ++i) {
        int ra = wm + i * 16 + l16;
        af[i] = *(const bf16x8*)(Asm + ra * 64 + p * 8);
      }
#pragma unroll
      for (int j = 0; j < NI; ++j) {
        int rb = wn + j * 16 + l16;
        bv[j] = *(const bf16x8*)(Bsm + rb * 64 + p * 8);
      }
#pragma unroll
      for (int i = 0; i < MI; ++i)
#pragma unroll
        for (int j = 0; j < NI; ++j)
          acc[i][j] = __builtin_amdgcn_mfma_f32_16x16x32_bf16(af[i], bv[j], acc[i][j], 0, 0, 0);
    }
    __syncthreads();  // LDS reads done before next stage overwrites
  }

  // epilogue: C/D layout col = lane&15, row = quad*4 + reg
  if (EPI == 1) {
    unsigned short* C = (unsigned short*)C0out;
#pragma unroll
    for (int i = 0; i < MI; ++i) {
      long m0 = tm0 + wm + i * 16 + quad * 4;
#pragma unroll
      for (int j = 0; j < NI; ++j) {
        int n = (int)tn0 + wn + j * 16 + l16;
        float bvs = bias[n];
#pragma unroll
        for (int r = 0; r < 4; ++r) {
          float v = acc[i][j][r] + bvs;
          v = fmaxf(v, 0.0f);
          C[(size_t)(m0 + r) * N + n] = f2bf(v);
        }
      }
    }
  } else {  // EPI == 2: split p_l (bf16) / p_r (f32), both stride 256
    unsigned short* PL = (unsigned short*)C0out;
    float* PR = (float*)C1out;
#pragma unroll
    for (int i = 0; i < MI; ++i) {
      long m0 = tm0 + wm + i * 16 + quad * 4;
#pragma unroll
      for (int j = 0; j < NI; ++j) {
        int n = (int)tn0 + wn + j * 16 + l16;  // 16-aligned per (j): branch is uniform
        if (n < 256) {
#pragma unroll
          for (int r = 0; r < 4; ++r) PL[(size_t)(m0 + r) * 256 + n] = f2bf(acc[i][j][r]);
        } else {
#pragma unroll
          for (int r = 0; r < 4; ++r) PR[(size_t)(m0 + r) * 256 + (n - 256)] = acc[i][j][r];
        }
      }
    }
  }
}

// ---------------- layer-2 gather + bias + p_r + log_softmax (fused) ----------------
// 128 threads/block, thread t owns cols {2t, 2t+1}; p_l read as packed 2xbf16.
__global__ __launch_bounds__(128) void gather2_final_kernel(const unsigned short* __restrict__ pl,
                                                            const float* __restrict__ pr,
                                                            const int* __restrict__ offs,
                                                            const int* __restrict__ csr,
                                                            const float* __restrict__ b2,
                                                            float* __restrict__ out) {
  int i = blockIdx.x;
  int t = threadIdx.x;  // 0..127
  int beg = offs[i], end = offs[i + 1];
  float a0 = 0.f, a1 = 0.f;
  for (int j = beg; j < end; ++j) {
    int s = __builtin_amdgcn_readfirstlane(csr[j]);  // block-uniform -> SGPR
    unsigned int u = ((const unsigned int*)(pl + (size_t)s * 256))[t];
    a0 += bf2f((unsigned short)(u & 0xffffu));
    a1 += bf2f((unsigned short)(u >> 16));
  }
  float inv = 1.0f / (float)max(end - beg, 1);
  float2 bv = ((const float2*)b2)[t];
  float2 pv = ((const float2*)(pr + (size_t)i * 256))[t];
  float v0 = a0 * inv + bv.x + pv.x;
  float v1 = a1 * inv + bv.y + pv.y;

  __shared__ float sm[2], ss[2];
  int w = t >> 6;
  float m = fmaxf(v0, v1);
#pragma unroll
  for (int o = 32; o > 0; o >>= 1) m = fmaxf(m, __shfl_xor(m, o, 64));
  if ((t & 63) == 0) sm[w] = m;
  __syncthreads();
  m = fmaxf(sm[0], sm[1]);

  float s = __expf(v0 - m) + __expf(v1 - m);
#pragma unroll
  for (int o = 32; o > 0; o >>= 1) s += __shfl_xor(s, o, 64);
  if ((t & 63) == 0) ss[w] = s;
  __syncthreads();
  float ls = logf(ss[0] + ss[1]);

  float2 o2 = {v0 - m - ls, v1 - m - ls};
  ((float2*)(out + (size_t)i * OUTD))[t] = o2;
}

// ---------------- workspace layout (bytes) ----------------
static constexpr size_t OFF_A1 = 0;
static constexpr size_t OFF_W1 = OFF_A1 + (size_t)M_PAD * 2048 * 2;
static constexpr size_t OFF_HB = OFF_W1 + (size_t)HID * 2048 * 2;
static constexpr size_t OFF_W2 = OFF_HB + (size_t)M_PAD * HID * 2;
static constexpr size_t OFF_XBF = OFF_W2 - (size_t)NN * IN_DIM * 2;  // tail of h_b
static constexpr size_t OFF_DEG = OFF_W2 + (size_t)512 * HID * 2;
static constexpr size_t OFF_OFFS = OFF_DEG + (size_t)NN * 4;
static constexpr size_t OFF_CUR = OFF_OFFS + (size_t)(NN + 4) * 4;
static constexpr size_t OFF_CSR = OFF_CUR + (size_t)NN * 4;
static constexpr size_t OFF_PL = OFF_A1;                              // alias: A1 dead after gemm1
static constexpr size_t OFF_PR = OFF_PL + (size_t)M_PAD * 256 * 2;

extern "C" void kernel_launch(void* const* d_in, const int* in_sizes, int n_in,
                              void* d_out, int out_size, void* d_ws, size_t ws_size,
                              hipStream_t stream) {
  const float* x = (const float*)d_in[0];
  const int* ei = (const int*)d_in[1];
  const int* src = ei;
  const int* dst = ei + NE;
  const float* W1_l = (const float*)d_in[2];
  const float* b1_l = (const float*)d_in[3];
  const float* W1_r = (const float*)d_in[4];
  const float* W2_l = (const float*)d_in[5];
  const float* b2_l = (const float*)d_in[6];
  const float* W2_r = (const float*)d_in[7];
  float* out = (float*)d_out;

  char* ws = (char*)d_ws;
  unsigned short* A1 = (unsigned short*)(ws + OFF_A1);
  unsigned short* w1cat = (unsigned short*)(ws + OFF_W1);
  unsigned short* h_b = (unsigned short*)(ws + OFF_HB);
  unsigned short* x_bf = (unsigned short*)(ws + OFF_XBF);
  unsigned short* w2cat = (unsigned short*)(ws + OFF_W2);
  int* deg = (int*)(ws + OFF_DEG);
  int* offs = (int*)(ws + OFF_OFFS);
  int* cur = (int*)(ws + OFF_CUR);
  int* csr = (int*)(ws + OFF_CSR);
  unsigned short* pl = (unsigned short*)(ws + OFF_PL);
  float* pr = (float*)(ws + OFF_PR);

  // zero counters + A1 pad rows (ws is poisoned 0xAA before every call)
  hipMemsetAsync(deg, 0, (size_t)NN * 4, stream);
  hipMemsetAsync(A1 + (size_t)NN * 2048, 0, (size_t)(M_PAD - NN) * 2048 * 2, stream);

  // fused prep: weight converts + x->bf16 + degree count
  prep_kernel<<<PREP_NB, 256, 0, stream>>>(W1_l, W1_r, W2_l, W2_r, x, dst,
                                           w1cat, w2cat, x_bf, deg);
  scan_kernel<<<1, 256, 0, stream>>>(deg, offs, cur);
  bin_kernel<<<(NE + 255) / 256, 256, 0, stream>>>(src, dst, cur, csr);

  // A1 = [mean | x] bf16 via CSR gather from bf16 x (no atomics)
  gather1_kernel<<<NN, 256, 0, stream>>>(x_bf, offs, csr, A1);

  // h = relu(A1 @ w1cat^T + b1)  -> bf16 [10112][4096]; GM=32 group swizzle
  gemm_kernel<128, 2048, 4096, 79, 32, 32, 1>
      <<<79 * 32, 256, 0, stream>>>(A1, w1cat, b1_l, h_b, nullptr);
  // [p_l | p_r] = h @ w2cat^T -> p_l bf16 [10112][256], p_r f32 [10112][256]; GM=64
  gemm_kernel<64, 4096, 512, 158, 4, 64, 2>
      <<<158 * 4, 256, 0, stream>>>(h_b, w2cat, nullptr, pl, pr);

  // mean of p_l over in-edges + bias + p_r, then log_softmax
  gather2_final_kernel<<<NN, 128, 0, stream>>>(pl, pr, offs, csr, b2_l, out);
}

// Round 6
// 444.008 us; speedup vs baseline: 3.6219x; 1.0059x over previous
//
#include <hip/hip_runtime.h>
#include <cstdint>
#include <cstddef>

#define DEVINL __device__ __forceinline__

typedef __bf16 bf16x8 __attribute__((ext_vector_type(8)));
typedef float f32x4 __attribute__((ext_vector_type(4)));

static constexpr int NN = 10000;     // nodes
static constexpr int NE = 80000;     // edges
static constexpr int IN_DIM = 1024;
static constexpr int HID = 4096;
static constexpr int OUTD = 256;
static constexpr int M_PAD = 10112;  // 79*128 (also 158*64)

// fp32 -> bf16 round-nearest-even
DEVINL unsigned short f2bf(float f) {
  unsigned int u = __builtin_bit_cast(unsigned int, f);
  u += 0x7fffu + ((u >> 16) & 1u);
  return (unsigned short)(u >> 16);
}
DEVINL float bf2f(unsigned short h) {
  unsigned int u = ((unsigned int)h) << 16;
  return __builtin_bit_cast(float, u);
}

// async global->LDS, 16B per lane; LDS dest is wave-uniform base + lane*16
DEVINL void ld_lds16(const void* g, void* l) {
  __builtin_amdgcn_global_load_lds(
      (const __attribute__((address_space(1))) unsigned int*)g,
      (__attribute__((address_space(3))) unsigned int*)l, 16, 0, 0);
}

// ---------------- fused prep: conv_w1 + conv_w2 + x->bf16 + degree count ----------------
static constexpr int PREP_B1 = 8192;
static constexpr int PREP_B2 = PREP_B1 + 2048;
static constexpr int PREP_B3 = PREP_B2 + 10000;
static constexpr int PREP_NB = PREP_B3 + 313;

__global__ __launch_bounds__(256) void prep_kernel(
    const float* __restrict__ W1l, const float* __restrict__ W1r,
    const float* __restrict__ W2l, const float* __restrict__ W2r,
    const float* __restrict__ x, const int* __restrict__ dst,
    unsigned short* __restrict__ w1cat, unsigned short* __restrict__ w2cat,
    unsigned short* __restrict__ x_bf, int* __restrict__ deg) {
  int b = blockIdx.x;
  int t = threadIdx.x;
  if (b < PREP_B1) {  // w1cat [4096][2048]: row n = [W1_l row n | W1_r row n]
    int g = b * 256 + t;
    int n = g >> 9;
    int kg = g & 511;
    const float* s = (kg < 256) ? (W1l + (size_t)n * 1024 + kg * 4)
                                : (W1r + (size_t)n * 1024 + (kg - 256) * 4);
    float4 v = *(const float4*)s;
    ushort4 p = {f2bf(v.x), f2bf(v.y), f2bf(v.z), f2bf(v.w)};
    ((ushort4*)w1cat)[g] = p;
  } else if (b < PREP_B2) {  // w2cat [512][4096]: rows 0..255 = W2_l, 256..511 = W2_r
    int g = (b - PREP_B1) * 256 + t;
    int n = g >> 10;
    int kg = g & 1023;
    const float* s = (n < 256) ? (W2l + (size_t)n * 4096 + kg * 4)
                               : (W2r + (size_t)(n - 256) * 4096 + kg * 4);
    float4 v = *(const float4*)s;
    ushort4 p = {f2bf(v.x), f2bf(v.y), f2bf(v.z), f2bf(v.w)};
    ((ushort4*)w2cat)[g] = p;
  } else if (b < PREP_B3) {  // x -> bf16, [10000][1024]
    int g = (b - PREP_B2) * 256 + t;
    int i = g >> 8;
    int kg = g & 255;
    float4 v = ((const float4*)(x + (size_t)i * IN_DIM))[kg];
    ushort4 p = {f2bf(v.x), f2bf(v.y), f2bf(v.z), f2bf(v.w)};
    ((ushort4*)(x_bf + (size_t)i * IN_DIM))[kg] = p;
  } else {  // degree count
    int e = (b - PREP_B3) * 256 + t;
    if (e < NE) atomicAdd(&deg[dst[e]], 1);
  }
}

// one-block exclusive scan over NN degrees -> offs[0..NN] and cursor copy cur[]
__global__ __launch_bounds__(256) void scan_kernel(const int* __restrict__ deg,
                                                   int* __restrict__ offs,
                                                   int* __restrict__ cur) {
  __shared__ int part[256];
  constexpr int NPT = 40;  // 256*40 = 10240 >= NN
  int t = threadIdx.x;
  int base = t * NPT;
  int s = 0;
  for (int j = 0; j < NPT; ++j) {
    int n = base + j;
    s += (n < NN) ? deg[n] : 0;
  }
  part[t] = s;
  __syncthreads();
  for (int o = 1; o < 256; o <<= 1) {  // Hillis-Steele inclusive scan
    int v = (t >= o) ? part[t - o] : 0;
    __syncthreads();
    part[t] += v;
    __syncthreads();
  }
  int pre = (t > 0) ? part[t - 1] : 0;
  for (int j = 0; j < NPT; ++j) {
    int n = base + j;
    if (n < NN) {
      offs[n] = pre;
      cur[n] = pre;
      pre += deg[n];
    }
  }
  if (t == 255) offs[NN] = part[255];  // == NE
}

// bin edges: csr[cur[dst]++] = src  (cur pre-seeded with offs by scan)
__global__ void bin_kernel(const int* __restrict__ src, const int* __restrict__ dst,
                           int* __restrict__ cur, int* __restrict__ csr) {
  int e = blockIdx.x * 256 + threadIdx.x;
  if (e < NE) {
    int p = atomicAdd(&cur[dst[e]], 1);
    csr[p] = src[e];
  }
}

// ---------------- layer-1 gather (bf16 source): A1 = [mean_agg(x) | x] ----------------
// grid = M_PAD blocks; rows >= NN are zero pad (absorbs the pad memset).
// Edge loop unrolled x2: two independent 2KB row loads in flight.
__global__ __launch_bounds__(256) void gather1_kernel(const unsigned short* __restrict__ x_bf,
                                                      const int* __restrict__ offs,
                                                      const int* __restrict__ csr,
                                                      unsigned short* __restrict__ A1) {
  int i = blockIdx.x;
  int t = threadIdx.x;  // 256 threads x ushort4 = 1024 bf16 = one row
  unsigned short* row = A1 + (size_t)i * 2048;
  if (i >= NN) {
    ushort4 z = {0, 0, 0, 0};
    ((ushort4*)row)[t] = z;
    ((ushort4*)(row + 1024))[t] = z;
    return;
  }
  int beg = offs[i], end = offs[i + 1];
  float4 a0 = {0.f, 0.f, 0.f, 0.f}, a1 = {0.f, 0.f, 0.f, 0.f};
  int j = beg;
  for (; j + 2 <= end; j += 2) {
    int s0 = __builtin_amdgcn_readfirstlane(csr[j]);
    int s1 = __builtin_amdgcn_readfirstlane(csr[j + 1]);
    ushort4 u0 = ((const ushort4*)(x_bf + (size_t)s0 * IN_DIM))[t];
    ushort4 u1 = ((const ushort4*)(x_bf + (size_t)s1 * IN_DIM))[t];
    a0.x += bf2f(u0.x); a0.y += bf2f(u0.y); a0.z += bf2f(u0.z); a0.w += bf2f(u0.w);
    a1.x += bf2f(u1.x); a1.y += bf2f(u1.y); a1.z += bf2f(u1.z); a1.w += bf2f(u1.w);
  }
  if (j < end) {
    int s0 = __builtin_amdgcn_readfirstlane(csr[j]);
    ushort4 u0 = ((const ushort4*)(x_bf + (size_t)s0 * IN_DIM))[t];
    a0.x += bf2f(u0.x); a0.y += bf2f(u0.y); a0.z += bf2f(u0.z); a0.w += bf2f(u0.w);
  }
  float inv = 1.0f / (float)max(end - beg, 1);
  ushort4 ub = ((const ushort4*)(x_bf + (size_t)i * IN_DIM))[t];
  ushort4 pa = {f2bf((a0.x + a1.x) * inv), f2bf((a0.y + a1.y) * inv),
                f2bf((a0.z + a1.z) * inv), f2bf((a0.w + a1.w) * inv)};
  ((ushort4*)row)[t] = pa;           // cols 0..1023  = mean
  ((ushort4*)(row + 1024))[t] = ub;  // cols 1024..2047 = x
}

// ---------------- bf16 MFMA GEMM, templated BK in {64,128} ----------------
// C[M_PAD,N] = A[M_PAD,K] * Bt[N,K]^T. BN=128 fixed; BM in {64,128}; 4 waves 2x2.
// LDS row = BK bf16 = BK/8 chunks of 16 B. Chunk swizzle: physical chunk p of row r holds
// logical chunk p ^ (r & 7) (low-3-bit XOR). global_load_lds stays lane-contiguous (source
// column swizzled); ds_read_b128 at p=(kk*4+quad)^(l16&7) -> 2-way bank aliasing (free,
// SQ_LDS_BANK_CONFLICT==0 measured). BK=128 doubles MFMA per barrier-pair (for GEMM2 where
// the extra LDS is not occupancy-binding).
// EPI 1: C0 = bf16 [M][N], relu(acc + bias)   (layer 1)
// EPI 2: split: n<256 -> C0 bf16 [M][256] (p_l), n>=256 -> C1 f32 [M][256] (p_r)
template <int BM, int BK, int K, int N, int NUMM, int NUMN, int GM, int EPI>
__global__ __launch_bounds__(256) void gemm_kernel(const unsigned short* __restrict__ A,
                                                   const unsigned short* __restrict__ Bt,
                                                   const float* __restrict__ bias,
                                                   void* __restrict__ C0out,
                                                   void* __restrict__ C1out) {
  constexpr int BN = 128;
  constexpr int MI = BM / 32;             // 16-row tiles per wave (m)
  constexpr int NI = 4;                   // 16-col tiles per wave (n)
  constexpr int CPR = BK / 8;             // 16B chunks per LDS row
  constexpr int SA = BM * CPR / 256;      // staging rounds for A (256 thr x 16B)
  constexpr int SB = BN * CPR / 256;
  constexpr int KK = BK / 32;             // MFMA k-steps per tile
  __shared__ unsigned short Asm[BM * BK];
  __shared__ unsigned short Bsm[BN * BK];

  // grouped swizzle
  constexpr int NPG = GM * NUMN;
  const int pid = blockIdx.x;
  const int gid = pid / NPG;
  const int first_m = gid * GM;
  const int sz = (NUMM - first_m < GM) ? (NUMM - first_m) : GM;
  const int local = pid % NPG;
  const int pm = first_m + local % sz;
  const int pn = local / sz;

  const int tid = threadIdx.x;
  const int lane = tid & 63;
  const int wave = tid >> 6;
  const int quad = lane >> 4;
  const int l16 = lane & 15;
  const int wm = (wave & 1) * (BM / 2);
  const int wn = (wave >> 1) * 64;
  const long tm0 = (long)pm * BM;
  const long tn0 = (long)pn * BN;

  f32x4 acc[MI][NI];
#pragma unroll
  for (int i = 0; i < MI; ++i)
#pragma unroll
    for (int j = 0; j < NI; ++j) acc[i][j] = (f32x4){0.f, 0.f, 0.f, 0.f};

  // staging: chunk c = s*256 + tid; row r = c / CPR; physical slot = c % CPR;
  // source logical chunk g = slot ^ (r & 7)  -> global col g*8
  const unsigned short* aSrc[SA];
  unsigned short* aDst[SA];
  const unsigned short* bSrc[SB];
  unsigned short* bDst[SB];
#pragma unroll
  for (int s = 0; s < SA; ++s) {
    int c = s * 256 + wave * 64 + lane;
    int r = c / CPR;
    int g = (c % CPR) ^ (r & 7);
    aSrc[s] = A + (size_t)(tm0 + r) * K + g * 8;
    aDst[s] = Asm + s * 2048 + wave * 512;  // wave-uniform base
  }
#pragma unroll
  for (int s = 0; s < SB; ++s) {
    int c = s * 256 + wave * 64 + lane;
    int r = c / CPR;
    int g = (c % CPR) ^ (r & 7);
    bSrc[s] = Bt + (size_t)(tn0 + r) * K + g * 8;
    bDst[s] = Bsm + s * 2048 + wave * 512;
  }

  const int l7 = l16 & 7;

  for (int k0 = 0; k0 < K; k0 += BK) {
#pragma unroll
    for (int s = 0; s < SA; ++s) ld_lds16(aSrc[s] + k0, aDst[s]);
#pragma unroll
    for (int s = 0; s < SB; ++s) ld_lds16(bSrc[s] + k0, bDst[s]);
    __syncthreads();  // drains vmcnt -> LDS tiles complete

#pragma unroll
    for (int kk = 0; kk < KK; ++kk) {
      const int p = (kk * 4 + quad) ^ l7;  // physical chunk for this frag
      bf16x8 af[MI], bv[NI];
#pragma unroll
      for (int i = 0; i < MI; ++i) {
        int ra = wm + i * 16 + l16;
        af[i] = *(const bf16x8*)(Asm + ra * BK + p * 8);
      }
#pragma unroll
      for (int j = 0; j < NI; ++j) {
        int rb = wn + j * 16 + l16;
        bv[j] = *(const bf16x8*)(Bsm + rb * BK + p * 8);
      }
#pragma unroll
      for (int i = 0; i < MI; ++i)
#pragma unroll
        for (int j = 0; j < NI; ++j)
          acc[i][j] = __builtin_amdgcn_mfma_f32_16x16x32_bf16(af[i], bv[j], acc[i][j], 0, 0, 0);
    }
    __syncthreads();  // LDS reads done before next stage overwrites
  }

  // epilogue: C/D layout col = lane&15, row = quad*4 + reg
  if (EPI == 1) {
    unsigned short* C = (unsigned short*)C0out;
#pragma unroll
    for (int i = 0; i < MI; ++i) {
      long m0 = tm0 + wm + i * 16 + quad * 4;
#pragma unroll
      for (int j = 0; j < NI; ++j) {
        int n = (int)tn0 + wn + j * 16 + l16;
        float bvs = bias[n];
#pragma unroll
        for (int r = 0; r < 4; ++r) {
          float v = acc[i][j][r] + bvs;
          v = fmaxf(v, 0.0f);
          C[(size_t)(m0 + r) * N + n] = f2bf(v);
        }
      }
    }
  } else {  // EPI == 2: split p_l (bf16) / p_r (f32), both stride 256
    unsigned short* PL = (unsigned short*)C0out;
    float* PR = (float*)C1out;
#pragma unroll
    for (int i = 0; i < MI; ++i) {
      long m0 = tm0 + wm + i * 16 + quad * 4;
#pragma unroll
      for (int j = 0; j < NI; ++j) {
        int n = (int)tn0 + wn + j * 16 + l16;  // 16-aligned per (j): branch is uniform
        if (n < 256) {
#pragma unroll
          for (int r = 0; r < 4; ++r) PL[(size_t)(m0 + r) * 256 + n] = f2bf(acc[i][j][r]);
        } else {
#pragma unroll
          for (int r = 0; r < 4; ++r) PR[(size_t)(m0 + r) * 256 + (n - 256)] = acc[i][j][r];
        }
      }
    }
  }
}

// ---------------- layer-2 gather + bias + p_r + log_softmax (fused) ----------------
// 128 threads/block, thread t owns cols {2t, 2t+1}; p_l read as packed 2xbf16; edge loop x2.
__global__ __launch_bounds__(128) void gather2_final_kernel(const unsigned short* __restrict__ pl,
                                                            const float* __restrict__ pr,
                                                            const int* __restrict__ offs,
                                                            const int* __restrict__ csr,
                                                            const float* __restrict__ b2,
                                                            float* __restrict__ out) {
  int i = blockIdx.x;
  int t = threadIdx.x;  // 0..127
  int beg = offs[i], end = offs[i + 1];
  float a0 = 0.f, a1 = 0.f, c0 = 0.f, c1 = 0.f;
  int j = beg;
  for (; j + 2 <= end; j += 2) {
    int s0 = __builtin_amdgcn_readfirstlane(csr[j]);
    int s1 = __builtin_amdgcn_readfirstlane(csr[j + 1]);
    unsigned int u0 = ((const unsigned int*)(pl + (size_t)s0 * 256))[t];
    unsigned int u1 = ((const unsigned int*)(pl + (size_t)s1 * 256))[t];
    a0 += bf2f((unsigned short)(u0 & 0xffffu));
    a1 += bf2f((unsigned short)(u0 >> 16));
    c0 += bf2f((unsigned short)(u1 & 0xffffu));
    c1 += bf2f((unsigned short)(u1 >> 16));
  }
  if (j < end) {
    int s0 = __builtin_amdgcn_readfirstlane(csr[j]);
    unsigned int u0 = ((const unsigned int*)(pl + (size_t)s0 * 256))[t];
    a0 += bf2f((unsigned short)(u0 & 0xffffu));
    a1 += bf2f((unsigned short)(u0 >> 16));
  }
  float inv = 1.0f / (float)max(end - beg, 1);
  float2 bv = ((const float2*)b2)[t];
  float2 pv = ((const float2*)(pr + (size_t)i * 256))[t];
  float v0 = (a0 + c0) * inv + bv.x + pv.x;
  float v1 = (a1 + c1) * inv + bv.y + pv.y;

  __shared__ float sm[2], ss[2];
  int w = t >> 6;
  float m = fmaxf(v0, v1);
#pragma unroll
  for (int o = 32; o > 0; o >>= 1) m = fmaxf(m, __shfl_xor(m, o, 64));
  if ((t & 63) == 0) sm[w] = m;
  __syncthreads();
  m = fmaxf(sm[0], sm[1]);

  float s = __expf(v0 - m) + __expf(v1 - m);
#pragma unroll
  for (int o = 32; o > 0; o >>= 1) s += __shfl_xor(s, o, 64);
  if ((t & 63) == 0) ss[w] = s;
  __syncthreads();
  float ls = logf(ss[0] + ss[1]);

  float2 o2 = {v0 - m - ls, v1 - m - ls};
  ((float2*)(out + (size_t)i * OUTD))[t] = o2;
}

// ---------------- workspace layout (bytes) ----------------
static constexpr size_t OFF_A1 = 0;
static constexpr size_t OFF_W1 = OFF_A1 + (size_t)M_PAD * 2048 * 2;
static constexpr size_t OFF_HB = OFF_W1 + (size_t)HID * 2048 * 2;
static constexpr size_t OFF_W2 = OFF_HB + (size_t)M_PAD * HID * 2;
static constexpr size_t OFF_XBF = OFF_W2 - (size_t)NN * IN_DIM * 2;  // tail of h_b
static constexpr size_t OFF_DEG = OFF_W2 + (size_t)512 * HID * 2;
static constexpr size_t OFF_OFFS = OFF_DEG + (size_t)NN * 4;
static constexpr size_t OFF_CUR = OFF_OFFS + (size_t)(NN + 4) * 4;
static constexpr size_t OFF_CSR = OFF_CUR + (size_t)NN * 4;
static constexpr size_t OFF_PL = OFF_A1;                              // alias: A1 dead after gemm1
static constexpr size_t OFF_PR = OFF_PL + (size_t)M_PAD * 256 * 2;

extern "C" void kernel_launch(void* const* d_in, const int* in_sizes, int n_in,
                              void* d_out, int out_size, void* d_ws, size_t ws_size,
                              hipStream_t stream) {
  const float* x = (const float*)d_in[0];
  const int* ei = (const int*)d_in[1];
  const int* src = ei;
  const int* dst = ei + NE;
  const float* W1_l = (const float*)d_in[2];
  const float* b1_l = (const float*)d_in[3];
  const float* W1_r = (const float*)d_in[4];
  const float* W2_l = (const float*)d_in[5];
  const float* b2_l = (const float*)d_in[6];
  const float* W2_r = (const float*)d_in[7];
  float* out = (float*)d_out;

  char* ws = (char*)d_ws;
  unsigned short* A1 = (unsigned short*)(ws + OFF_A1);
  unsigned short* w1cat = (unsigned short*)(ws + OFF_W1);
  unsigned short* h_b = (unsigned short*)(ws + OFF_HB);
  unsigned short* x_bf = (unsigned short*)(ws + OFF_XBF);
  unsigned short* w2cat = (unsigned short*)(ws + OFF_W2);
  int* deg = (int*)(ws + OFF_DEG);
  int* offs = (int*)(ws + OFF_OFFS);
  int* cur = (int*)(ws + OFF_CUR);
  int* csr = (int*)(ws + OFF_CSR);
  unsigned short* pl = (unsigned short*)(ws + OFF_PL);
  float* pr = (float*)(ws + OFF_PR);

  // zero degree counters (ws is poisoned 0xAA before every call)
  hipMemsetAsync(deg, 0, (size_t)NN * 4, stream);

  // fused prep: weight converts + x->bf16 + degree count
  prep_kernel<<<PREP_NB, 256, 0, stream>>>(W1_l, W1_r, W2_l, W2_r, x, dst,
                                           w1cat, w2cat, x_bf, deg);
  scan_kernel<<<1, 256, 0, stream>>>(deg, offs, cur);
  bin_kernel<<<(NE + 255) / 256, 256, 0, stream>>>(src, dst, cur, csr);

  // A1 = [mean | x] bf16 via CSR gather (no atomics); rows >= NN zeroed here
  gather1_kernel<<<M_PAD, 256, 0, stream>>>(x_bf, offs, csr, A1);

  // h = relu(A1 @ w1cat^T + b1)  -> bf16 [10112][4096]; BK=64, GM=32 group swizzle
  gemm_kernel<128, 64, 2048, 4096, 79, 32, 32, 1>
      <<<79 * 32, 256, 0, stream>>>(A1, w1cat, b1_l, h_b, nullptr);
  // [p_l | p_r] = h @ w2cat^T -> p_l bf16 [10112][256], p_r f32 [10112][256]; BK=128, GM=64
  gemm_kernel<64, 128, 4096, 512, 158, 4, 64, 2>
      <<<158 * 4, 256, 0, stream>>>(h_b, w2cat, nullptr, pl, pr);

  // mean of p_l over in-edges + bias + p_r, then log_softmax
  gather2_final_kernel<<<NN, 128, 0, stream>>>(pl, pr, offs, csr, b2_l, out);
}